// Round 11
// baseline (300.303 us; speedup 1.0000x reference)
//
#include <hip/hip_runtime.h>
#include <hip/hip_bf16.h>
#include <hip/hip_fp8.h>

// GNN: 2-layer GCN (N=50000, E=800000, F=128, H=256) + mean-pool (G=512) + MLP head (257->32->4)
// Key identity: segment_sum((xW)[src]*norm) == (segment_sum(x[src]*norm)) @ W  (GCN agg is linear)
//   prep:  cast_all (x->bf16, W transpose, zero deg/pool) -> hist(+epos) -> scan -> scatter
//   L1: agg128 -> a0; h1 = relu(a0 @ W1 + b1) -> FP8 e4m3   [MFMA, 128x128 dbuf tiles]
//   L2: agg256_fp8(h1) -> a1 bf16; gemm2_pool: relu(a1 @ W2 + b2) pooled into pool[G,256]
//   head: per-graph block: mean + 257->32->4 MLP
// R8/R9: agg at 8-XCD compulsory BYTES floor. R11/R13: sliced agg abandoned. R15: agg+GEMM
//   fusion refuted (TLP loss). R16: atomic-free scatter (348->322). R17: fp8 h1 table
//   (agg256 58.7->~33us, 322->297, absmax UNCHANGED).
// R18: GEMMs were latency-bound (occupancy 25%, MfmaUtil 4.6%, grid 391 = 1.5 blk/CU,
//   vmcnt(0) drain every K-step): (a) bn-split grid (391,2), 128x128 tiles, wave=64x32;
//   (b) 2-phase LDS double-buffer: STAGE(next) issued before compute(cur), one barrier/step.

#define NN 50000
#define EE 800000
#define FDIM 128
#define HDIM 256
#define GG 512
#define SCAN_NB ((NN + 255) / 256)

typedef __attribute__((ext_vector_type(8))) short short8;     // 8 bf16 = 4 VGPRs (MFMA A/B frag)
typedef __attribute__((ext_vector_type(4))) float floatx4;    // MFMA C/D frag
typedef __attribute__((ext_vector_type(2))) float floatx2;

__device__ __forceinline__ unsigned short f2bf(float f) {   // RNE
    unsigned u = __float_as_uint(f);
    return (unsigned short)((u + 0x7FFF + ((u >> 16) & 1)) >> 16);
}
__device__ __forceinline__ float bflo(unsigned v) { return __uint_as_float(v << 16); }
__device__ __forceinline__ float bfhi(unsigned v) { return __uint_as_float(v & 0xFFFF0000u); }

// fp8 e4m3 (OCP on gfx950) encode/decode via HW cvt; fallback to hip_fp8 type.
__device__ __forceinline__ unsigned char enc8(float v) {
#if defined(__has_builtin) && __has_builtin(__builtin_amdgcn_cvt_pk_fp8_f32)
    return (unsigned char)(__builtin_amdgcn_cvt_pk_fp8_f32(v, v, 0, false) & 0xFF);
#else
    __hip_fp8_e4m3 q(v);
    return (unsigned char)q.__x;
#endif
}
__device__ __forceinline__ void dec4(int d, float* f) {   // 4 fp8 bytes -> 4 floats
#if defined(__has_builtin) && __has_builtin(__builtin_amdgcn_cvt_pk_f32_fp8)
    floatx2 lo = __builtin_amdgcn_cvt_pk_f32_fp8(d, false);
    floatx2 hi = __builtin_amdgcn_cvt_pk_f32_fp8(d, true);
    f[0] = lo.x; f[1] = lo.y; f[2] = hi.x; f[3] = hi.y;
#else
    unsigned u = (unsigned)d;
    #pragma unroll
    for (int i = 0; i < 4; ++i) {
        __hip_fp8_e4m3 t; t.__x = (__hip_fp8_storage_t)((u >> (8 * i)) & 0xFF);
        f[i] = (float)t;
    }
#endif
}

// async global->LDS, 16B per lane. lds ptr must be wave-uniform (HW adds lane*16).
__device__ __forceinline__ void gload16(const void* g, void* l) {
    __builtin_amdgcn_global_load_lds((const __attribute__((address_space(1))) void*)g,
                                     (__attribute__((address_space(3))) void*)l, 16, 0, 0);
}

// ---------------- prep kernels ----------------

// hist + per-edge ordinal: epos[i] = old count of dst[i]. Scatter then needs no atomics.
__global__ void hist_kernel(const int* __restrict__ dst, int* __restrict__ deg,
                            int* __restrict__ epos, int e) {
    int i = blockIdx.x * blockDim.x + threadIdx.x;
    int stride = gridDim.x * blockDim.x;
    for (; i < e; i += stride) epos[i] = atomicAdd(&deg[dst[i]], 1);
}

__global__ __launch_bounds__(256) void scan_part(const int* __restrict__ deg,
                                                 int* __restrict__ row_off,
                                                 int* __restrict__ blk_sums,
                                                 float* __restrict__ dinv, int n) {
    __shared__ int s[256];
    int tid = threadIdx.x;
    int i = blockIdx.x * 256 + tid;
    int v = (i < n) ? deg[i] : 0;
    if (i < n) dinv[i] = rsqrtf((float)v + 1.0f);
    s[tid] = v;
    __syncthreads();
    #pragma unroll
    for (int off = 1; off < 256; off <<= 1) {
        int t = (tid >= off) ? s[tid - off] : 0;
        __syncthreads();
        s[tid] += t;
        __syncthreads();
    }
    if (i < n) row_off[i] = s[tid] - v;
    if (tid == 255) blk_sums[blockIdx.x] = s[255];
}

__global__ __launch_bounds__(256) void scan_sums(int* __restrict__ blk_sums, int nb) {
    __shared__ int s[256];
    int tid = threadIdx.x;
    int v = (tid < nb) ? blk_sums[tid] : 0;
    s[tid] = v;
    __syncthreads();
    #pragma unroll
    for (int off = 1; off < 256; off <<= 1) {
        int t = (tid >= off) ? s[tid - off] : 0;
        __syncthreads();
        s[tid] += t;
        __syncthreads();
    }
    if (tid < nb) blk_sums[tid] = s[tid] - v;
}

__global__ __launch_bounds__(256) void scan_add(int* __restrict__ row_off,
                                                const int* __restrict__ blk_sums,
                                                int n, int e) {
    int i = blockIdx.x * 256 + threadIdx.x;
    if (i < n) row_off[i] += blk_sums[blockIdx.x];
    if (i == 0) row_off[n] = e;
}

// atomic-free scatter: position = row_off[dst] + epos (ordinal captured in hist)
__global__ void scatter_kernel(const int* __restrict__ src, const int* __restrict__ dst,
                               const int* __restrict__ row_off, const int* __restrict__ epos,
                               const float* __restrict__ dinv,
                               int2* __restrict__ csr, int e) {
    int i = blockIdx.x * blockDim.x + threadIdx.x;
    int stride = gridDim.x * blockDim.x;
    for (; i < e; i += stride) {
        int s = src[i], d = dst[i];
        int pos = row_off[d] + epos[i];
        csr[pos] = make_int2(s, __float_as_int(dinv[s] * dinv[d]));
    }
}

// merged: x fp32->bf16 cast + W1/W2 transpose-cast + zero deg/pool. One dispatch.
#define XCHUNKS (NN * FDIM / 4)            // 1,600,000 float4 groups
#define CAST_TOTAL (XCHUNKS + FDIM * HDIM + HDIM * HDIM + NN / 4 + GG * HDIM / 4)
__global__ __launch_bounds__(256) void cast_all(const float* __restrict__ x,
                                                unsigned short* __restrict__ x_bf,
                                                const float* __restrict__ W1,
                                                unsigned short* __restrict__ W1t,
                                                const float* __restrict__ W2,
                                                unsigned short* __restrict__ W2t,
                                                int* __restrict__ deg,
                                                float* __restrict__ pool) {
    int idx = blockIdx.x * 256 + threadIdx.x;
    if (idx < XCHUNKS) {
        int i = idx * 4;
        float4 v = *(const float4*)&x[i];
        ushort4 o;
        o.x = f2bf(v.x); o.y = f2bf(v.y); o.z = f2bf(v.z); o.w = f2bf(v.w);
        *(ushort4*)&x_bf[i] = o;
        return;
    }
    int r = idx - XCHUNKS;
    if (r < FDIM * HDIM) {               // W1t[n][k] = bf16(W1[k][n]), K=128, Nc=256
        int nn = r / FDIM, k = r - nn * FDIM;
        W1t[r] = f2bf(W1[(size_t)k * HDIM + nn]);
        return;
    }
    r -= FDIM * HDIM;
    if (r < HDIM * HDIM) {               // W2t[n][k] = bf16(W2[k][n]), K=256, Nc=256
        int nn = r / HDIM, k = r - nn * HDIM;
        W2t[r] = f2bf(W2[(size_t)k * HDIM + nn]);
        return;
    }
    r -= HDIM * HDIM;
    if (r < NN / 4) {                    // zero deg (50000 % 4 == 0)
        int4 z = {0, 0, 0, 0};
        *(int4*)&deg[r * 4] = z;
        return;
    }
    r -= NN / 4;
    if (r < GG * HDIM / 4) {             // zero pool
        float4 z = {0.f, 0.f, 0.f, 0.f};
        *(float4*)&pool[r * 4] = z;
    }
}

// ---------------- GCN aggregation ----------------
// out[d] = sum_e in[src_e]*w_e + in[d]*dinv[d]^2
// wave-per-node, dwordx4 gathers (16B/lane). Wave split across edges.
// At the 8-XCD compulsory-traffic floor (FETCH = 8 x table bytes).
// NOTE: macro param must NOT be named 'w' (collides with .w member access).

#define FMA8(v, wgt) do { unsigned _u; \
    _u = (unsigned)(v).x; acc0 = fmaf(bflo(_u), (wgt), acc0); acc1 = fmaf(bfhi(_u), (wgt), acc1); \
    _u = (unsigned)(v).y; acc2 = fmaf(bflo(_u), (wgt), acc2); acc3 = fmaf(bfhi(_u), (wgt), acc3); \
    _u = (unsigned)(v).z; acc4 = fmaf(bflo(_u), (wgt), acc4); acc5 = fmaf(bfhi(_u), (wgt), acc5); \
    _u = (unsigned)(v).w; acc6 = fmaf(bflo(_u), (wgt), acc6); acc7 = fmaf(bfhi(_u), (wgt), acc7); } while (0)

__device__ __forceinline__ void fma16(const int4& g, float wgt, float* acc) {
    float f[16];
    dec4(g.x, f); dec4(g.y, f + 4); dec4(g.z, f + 8); dec4(g.w, f + 12);
    #pragma unroll
    for (int i = 0; i < 16; ++i) acc[i] = fmaf(f[i], wgt, acc[i]);
}

// L2 aggregation over the fp8 h1 table: row = 256 fp8 = 256B; 16 lanes x 16B per row;
// sub = lane>>4 -> 4 edge slots; 2 int4 gathers (8 edges) in flight. Output a1 bf16.
__global__ __launch_bounds__(256) void gcn_agg256_fp8(const unsigned char* __restrict__ in,
                                                      const int* __restrict__ row_off,
                                                      const int2* __restrict__ csr,
                                                      const float* __restrict__ dinv,
                                                      unsigned short* __restrict__ out, int n) {
    int wave = threadIdx.x >> 6;
    int lane = threadIdx.x & 63;
    int node = blockIdx.x * 4 + wave;
    if (node >= n) return;
    int sub = lane >> 4;          // edge slot 0..3
    int fl  = lane & 15;          // 16B chunk within 256B row
    float di = dinv[node];
    float w0 = (sub == 0) ? di * di : 0.f;

    float acc[16];
    {   // self term
        int4 sv = *(const int4*)&in[(size_t)node * 256 + fl * 16];
        float f[16];
        dec4(sv.x, f); dec4(sv.y, f + 4); dec4(sv.z, f + 8); dec4(sv.w, f + 12);
        #pragma unroll
        for (int i = 0; i < 16; ++i) acc[i] = f[i] * w0;
    }

    int beg = __builtin_amdgcn_readfirstlane(row_off[node]);
    int end = __builtin_amdgcn_readfirstlane(row_off[node + 1]);
    int cnt = end - beg;
    if (cnt > 0) {
        int nIter = (cnt + 7) >> 3;                    // 8 edges / iter (2 gathers)
        int base = beg;
        int last = end - 1;
        int i0 = base + sub, i1 = base + 4 + sub;
        int2 c0 = csr[i0 < end ? i0 : last];
        int2 c1 = csr[i1 < end ? i1 : last];
        for (int it = 0; it < nIter; ++it) {
            int4 g0 = *(const int4*)&in[(size_t)c0.x * 256 + fl * 16];
            int4 g1 = *(const int4*)&in[(size_t)c1.x * 256 + fl * 16];
            float we0 = (base + sub < end) ? __int_as_float(c0.y) : 0.f;
            float we1 = (base + 4 + sub < end) ? __int_as_float(c1.y) : 0.f;
            int nb = base + 8;
            int j0 = nb + sub, j1 = nb + 4 + sub;
            int2 n0 = csr[j0 < end ? j0 : last];
            int2 n1 = csr[j1 < end ? j1 : last];
            fma16(g0, we0, acc); fma16(g1, we1, acc);
            c0 = n0; c1 = n1; base = nb;
        }
    }
    // combine 4 edge-slots (lanes sharing fl differ in bits 4..5)
    #pragma unroll
    for (int i = 0; i < 16; ++i) {
        acc[i] += __shfl_xor(acc[i], 16);
        acc[i] += __shfl_xor(acc[i], 32);
    }
    if (sub == 0) {
        int4 o0, o1;
        o0.x = (int)((unsigned)f2bf(acc[0])  | ((unsigned)f2bf(acc[1])  << 16));
        o0.y = (int)((unsigned)f2bf(acc[2])  | ((unsigned)f2bf(acc[3])  << 16));
        o0.z = (int)((unsigned)f2bf(acc[4])  | ((unsigned)f2bf(acc[5])  << 16));
        o0.w = (int)((unsigned)f2bf(acc[6])  | ((unsigned)f2bf(acc[7])  << 16));
        o1.x = (int)((unsigned)f2bf(acc[8])  | ((unsigned)f2bf(acc[9])  << 16));
        o1.y = (int)((unsigned)f2bf(acc[10]) | ((unsigned)f2bf(acc[11]) << 16));
        o1.z = (int)((unsigned)f2bf(acc[12]) | ((unsigned)f2bf(acc[13]) << 16));
        o1.w = (int)((unsigned)f2bf(acc[14]) | ((unsigned)f2bf(acc[15]) << 16));
        *(int4*)&out[(size_t)node * 256 + fl * 16] = o0;
        *(int4*)&out[(size_t)node * 256 + fl * 16 + 8] = o1;
    }
}

__global__ __launch_bounds__(256) void gcn_agg128_bf16(const unsigned short* __restrict__ in,
                                                       const int* __restrict__ row_off,
                                                       const int2* __restrict__ csr,
                                                       const float* __restrict__ dinv,
                                                       unsigned short* __restrict__ out, int n) {
    int wave = threadIdx.x >> 6;
    int lane = threadIdx.x & 63;
    int node = blockIdx.x * 4 + wave;
    if (node >= n) return;
    int sub = lane >> 4;          // edge slot 0..3
    int fl  = lane & 15;          // 16B feature chunk within row
    float di = dinv[node];
    float w0 = (sub == 0) ? di * di : 0.f;

    float acc0, acc1, acc2, acc3, acc4, acc5, acc6, acc7;
    {   // self term
        int4 sv = *(const int4*)&in[(size_t)node * 128 + fl * 8];
        unsigned _u;
        _u = (unsigned)sv.x; acc0 = bflo(_u) * w0; acc1 = bfhi(_u) * w0;
        _u = (unsigned)sv.y; acc2 = bflo(_u) * w0; acc3 = bfhi(_u) * w0;
        _u = (unsigned)sv.z; acc4 = bflo(_u) * w0; acc5 = bfhi(_u) * w0;
        _u = (unsigned)sv.w; acc6 = bflo(_u) * w0; acc7 = bfhi(_u) * w0;
    }

    int beg = __builtin_amdgcn_readfirstlane(row_off[node]);
    int end = __builtin_amdgcn_readfirstlane(row_off[node + 1]);
    int cnt = end - beg;
    if (cnt > 0) {
        int nIter = (cnt + 7) >> 3;                    // 8 edges / iter (2 gathers)
        int base = beg;
        int last = end - 1;
        int i0 = base + sub, i1 = base + 4 + sub;
        int2 c0 = csr[i0 < end ? i0 : last];
        int2 c1 = csr[i1 < end ? i1 : last];
        for (int it = 0; it < nIter; ++it) {
            int4 g0 = *(const int4*)&in[(size_t)c0.x * 128 + fl * 8];
            int4 g1 = *(const int4*)&in[(size_t)c1.x * 128 + fl * 8];
            float we0 = (base + sub < end) ? __int_as_float(c0.y) : 0.f;
            float we1 = (base + 4 + sub < end) ? __int_as_float(c1.y) : 0.f;
            int nb = base + 8;
            int j0 = nb + sub, j1 = nb + 4 + sub;
            int2 n0 = csr[j0 < end ? j0 : last];
            int2 n1 = csr[j1 < end ? j1 : last];
            FMA8(g0, we0); FMA8(g1, we1);
            c0 = n0; c1 = n1; base = nb;
        }
    }
    // combine 4 edge-slots
    acc0 += __shfl_xor(acc0, 16); acc1 += __shfl_xor(acc1, 16);
    acc2 += __shfl_xor(acc2, 16); acc3 += __shfl_xor(acc3, 16);
    acc4 += __shfl_xor(acc4, 16); acc5 += __shfl_xor(acc5, 16);
    acc6 += __shfl_xor(acc6, 16); acc7 += __shfl_xor(acc7, 16);
    acc0 += __shfl_xor(acc0, 32); acc1 += __shfl_xor(acc1, 32);
    acc2 += __shfl_xor(acc2, 32); acc3 += __shfl_xor(acc3, 32);
    acc4 += __shfl_xor(acc4, 32); acc5 += __shfl_xor(acc5, 32);
    acc6 += __shfl_xor(acc6, 32); acc7 += __shfl_xor(acc7, 32);
    if (sub == 0) {
        int4 o;
        o.x = (int)((unsigned)f2bf(acc0) | ((unsigned)f2bf(acc1) << 16));
        o.y = (int)((unsigned)f2bf(acc2) | ((unsigned)f2bf(acc3) << 16));
        o.z = (int)((unsigned)f2bf(acc4) | ((unsigned)f2bf(acc5) << 16));
        o.w = (int)((unsigned)f2bf(acc6) | ((unsigned)f2bf(acc7) << 16));
        *(int4*)&out[(size_t)node * 128 + fl * 8] = o;
    }
}

// ---------------- bf16 MFMA GEMM, 128x128 tiles, dbuf, 8 waves (2x4 of 64x32) ----------------
// R18: grid (ceil(M/128), 2): bn = blockIdx.y*128. Per K-step each thread stages one 16B
// A-chunk + one 16B B-chunk via global_load_lds into LINEAR LDS (LDT=32). Double-buffered:
// STAGE(next) issued BEFORE compute(cur); single __syncthreads per step (drains vmcnt).
// Wave tile 64x32: acc[4][2]. Verified frag layouts (learn_hip m89/m91/m120).

__global__ __launch_bounds__(512, 2) void gemm1_mfma_bias_relu(
        const unsigned short* __restrict__ A,    // [M][128] bf16
        const unsigned short* __restrict__ Bt,   // [256][128] bf16
        const float* __restrict__ bias,          // [256] fp32
        unsigned char* __restrict__ C, int M) {  // [M][256] fp8 e4m3
    constexpr int K = FDIM, Nc = HDIM, LDT = 32;
    __shared__ unsigned short As[2][128 * LDT];  // 8KB per buffer
    __shared__ unsigned short Bs[2][128 * LDT];
    int tid = threadIdx.x;
    int lane = tid & 63, wave = tid >> 6;
    int wm = (wave >> 2) * 64;                   // 0 | 64
    int wn2 = (wave & 3) * 32;                   // 0,32,64,96
    int bm = blockIdx.x * 128;
    int bn = blockIdx.y * 128;
    int l15 = lane & 15, quad = lane >> 4;
    int srow = tid >> 2, sq = (tid & 3) * 8;     // staging: row 0..127, k-subchunk

    floatx4 zero = {0.f, 0.f, 0.f, 0.f};
    floatx4 acc[4][2];
    #pragma unroll
    for (int s = 0; s < 4; ++s)
        #pragma unroll
        for (int t = 0; t < 2; ++t) acc[s][t] = zero;

    // prologue: stage k0=0 into buf 0
    gload16(&A[(size_t)(bm + srow) * K + sq], &As[0][wave * 512]);
    gload16(&Bt[(size_t)(bn + srow) * K + sq], &Bs[0][wave * 512]);
    __syncthreads();
    int cur = 0;
    for (int k0 = 0; k0 < K; k0 += 32) {
        if (k0 + 32 < K) {   // stage next K-step into the other buffer
            gload16(&A[(size_t)(bm + srow) * K + k0 + 32 + sq], &As[cur ^ 1][wave * 512]);
            gload16(&Bt[(size_t)(bn + srow) * K + k0 + 32 + sq], &Bs[cur ^ 1][wave * 512]);
        }
        short8 af[4], bf[2];
        #pragma unroll
        for (int s = 0; s < 4; ++s)
            af[s] = *(const short8*)&As[cur][(wm + s * 16 + l15) * LDT + quad * 8];
        #pragma unroll
        for (int t = 0; t < 2; ++t)
            bf[t] = *(const short8*)&Bs[cur][(wn2 + t * 16 + l15) * LDT + quad * 8];
        #pragma unroll
        for (int s = 0; s < 4; ++s)
            #pragma unroll
            for (int t = 0; t < 2; ++t)
                acc[s][t] = __builtin_amdgcn_mfma_f32_16x16x32_bf16(af[s], bf[t], acc[s][t], 0, 0, 0);
        __syncthreads();                          // drains stage vmcnt + LDS reads
        cur ^= 1;
    }
    #pragma unroll
    for (int s = 0; s < 4; ++s) {
        int row0 = bm + wm + s * 16 + quad * 4;
        #pragma unroll
        for (int t = 0; t < 2; ++t) {
            int col = bn + wn2 + t * 16 + l15;
            float bb = bias[col];
            #pragma unroll
            for (int r = 0; r < 4; ++r) {
                int row = row0 + r;
                if (row < M)
                    C[(size_t)row * Nc + col] = enc8(fmaxf(acc[s][t][r] + bb, 0.f));
            }
        }
    }
}

// GEMM2 fused with mean-pool numerator: relu(a1 @ W2 + b2) segment-summed by batch[] into
// pool[G][256] via fp32 atomics (batch sorted -> mostly 1 atomic per 4-row group).
__global__ __launch_bounds__(512, 2) void gemm2_pool(
        const unsigned short* __restrict__ A,    // [M][256] bf16 (a1b)
        const unsigned short* __restrict__ Bt,   // [256][256] bf16
        const float* __restrict__ bias,          // [256] fp32
        const int* __restrict__ batch,           // [M] sorted graph ids
        float* __restrict__ pool, int M) {       // [G][256] fp32, pre-zeroed
    constexpr int K = HDIM, Nc = HDIM, LDT = 32;
    __shared__ unsigned short As[2][128 * LDT];
    __shared__ unsigned short Bs[2][128 * LDT];
    int tid = threadIdx.x;
    int lane = tid & 63, wave = tid >> 6;
    int wm = (wave >> 2) * 64;
    int wn2 = (wave & 3) * 32;
    int bm = blockIdx.x * 128;
    int bn = blockIdx.y * 128;
    int l15 = lane & 15, quad = lane >> 4;
    int srow = tid >> 2, sq = (tid & 3) * 8;

    floatx4 zero = {0.f, 0.f, 0.f, 0.f};
    floatx4 acc[4][2];
    #pragma unroll
    for (int s = 0; s < 4; ++s)
        #pragma unroll
        for (int t = 0; t < 2; ++t) acc[s][t] = zero;

    gload16(&A[(size_t)(bm + srow) * K + sq], &As[0][wave * 512]);
    gload16(&Bt[(size_t)(bn + srow) * K + sq], &Bs[0][wave * 512]);
    __syncthreads();
    int cur = 0;
    for (int k0 = 0; k0 < K; k0 += 32) {
        if (k0 + 32 < K) {
            gload16(&A[(size_t)(bm + srow) * K + k0 + 32 + sq], &As[cur ^ 1][wave * 512]);
            gload16(&Bt[(size_t)(bn + srow) * K + k0 + 32 + sq], &Bs[cur ^ 1][wave * 512]);
        }
        short8 af[4], bf[2];
        #pragma unroll
        for (int s = 0; s < 4; ++s)
            af[s] = *(const short8*)&As[cur][(wm + s * 16 + l15) * LDT + quad * 8];
        #pragma unroll
        for (int t = 0; t < 2; ++t)
            bf[t] = *(const short8*)&Bs[cur][(wn2 + t * 16 + l15) * LDT + quad * 8];
        #pragma unroll
        for (int s = 0; s < 4; ++s)
            #pragma unroll
            for (int t = 0; t < 2; ++t)
                acc[s][t] = __builtin_amdgcn_mfma_f32_16x16x32_bf16(af[s], bf[t], acc[s][t], 0, 0, 0);
        __syncthreads();
        cur ^= 1;
    }
    // epilogue: segment-sum 4-row groups into pool
    #pragma unroll
    for (int s = 0; s < 4; ++s) {
        int row0 = bm + wm + s * 16 + quad * 4;
        if (row0 >= M) continue;
        bool full = (row0 + 3 < M);
        int gA = batch[row0];
        int gB = full ? batch[row0 + 3] : gA;
        bool same = full && (gA == gB);
        #pragma unroll
        for (int t = 0; t < 2; ++t) {
            int col = bn + wn2 + t * 16 + l15;
            float bb = bias[col];
            if (same) {
                float v = fmaxf(acc[s][t][0] + bb, 0.f) + fmaxf(acc[s][t][1] + bb, 0.f)
                        + fmaxf(acc[s][t][2] + bb, 0.f) + fmaxf(acc[s][t][3] + bb, 0.f);
                atomicAdd(&pool[(size_t)gA * Nc + col], v);
            } else {
                #pragma unroll
                for (int r = 0; r < 4; ++r) {
                    int row = row0 + r;
                    if (row < M) {
                        float v = fmaxf(acc[s][t][r] + bb, 0.f);
                        atomicAdd(&pool[(size_t)batch[row] * Nc + col], v);
                    }
                }
            }
        }
    }
}

// ---------------- head: one block per graph, reads pooled sums ----------------

__device__ __forceinline__ int lower_bound_i(const int* __restrict__ a, int n, int v) {
    int lo = 0, hi = n;
    while (lo < hi) {
        int mid = (lo + hi) >> 1;
        if (a[mid] < v) lo = mid + 1; else hi = mid;
    }
    return lo;
}

__global__ __launch_bounds__(256) void head_kernel(const float* __restrict__ pool,
                                                   const int* __restrict__ batch,
                                                   const float* __restrict__ num_atoms,
                                                   const float* __restrict__ W3, const float* __restrict__ b3,
                                                   const float* __restrict__ W4, const float* __restrict__ b4,
                                                   float* __restrict__ out, int n) {
    int g = blockIdx.x;
    int tid = threadIdx.x;
    __shared__ int s_lo, s_hi;
    if (tid == 0) {
        s_lo = lower_bound_i(batch, n, g);
        s_hi = lower_bound_i(batch, n, g + 1);
    }
    __syncthreads();
    float cnt = (float)(s_hi - s_lo);

    __shared__ float zin[HDIM + 1];
    __shared__ float z[32];
    zin[tid] = pool[(size_t)g * HDIM + tid] / fmaxf(cnt, 1.0f);
    if (tid == 0) zin[HDIM] = num_atoms[g];
    __syncthreads();
    if (tid < 32) {
        float a = b3[tid];
        for (int k = 0; k < HDIM + 1; ++k) a = fmaf(zin[k], W3[k * 32 + tid], a);
        z[tid] = fmaxf(a, 0.f);
    }
    __syncthreads();
    if (tid < 4) {
        float a = b4[tid];
        #pragma unroll
        for (int k = 0; k < 32; ++k) a = fmaf(z[k], W4[k * 4 + tid], a);
        out[g * 4 + tid] = a;
    }
}

// ---------------- launch ----------------

extern "C" void kernel_launch(void* const* d_in, const int* in_sizes, int n_in,
                              void* d_out, int out_size, void* d_ws, size_t ws_size,
                              hipStream_t stream) {
    const float* x         = (const float*)d_in[0];
    const int*   edge_idx  = (const int*)d_in[1];
    const int*   batch     = (const int*)d_in[2];
    const float* num_atoms = (const float*)d_in[3];
    const float* W1 = (const float*)d_in[4];
    const float* b1 = (const float*)d_in[5];
    const float* W2 = (const float*)d_in[6];
    const float* b2 = (const float*)d_in[7];
    const float* W3 = (const float*)d_in[8];
    const float* b3 = (const float*)d_in[9];
    const float* W4 = (const float*)d_in[10];
    const float* b4 = (const float*)d_in[11];
    float* out = (float*)d_out;

    const int n = NN, e = EE;
    const int* e_src = edge_idx;
    const int* e_dst = edge_idx + e;

    // workspace (256B aligned). Lifetime aliasing:
    //   P (25.6MB): {x_bf [N,128]bf16 ; a0b [N,128]bf16} live through gemm1,
    //               then whole P reused as a1b [N,256]bf16 (agg256 out).
    //   Q (12.8MB): h1f8 [N,256]fp8 (gemm1 out, dead after agg256). Also absorbs GEMM
    //               staging over-reads past row M.
    //   pool (512KB): [G,256] fp32 pooled sums (gemm2_pool out -> head).
    char* ws = (char*)d_ws;
    size_t off = 0;
    auto carve = [&](size_t bytes) -> void* {
        void* p = ws + off;
        off = (off + bytes + 255) & ~(size_t)255;
        return p;
    };
    int*   deg_i    = (int*)carve((size_t)n * 4);
    int*   row_off  = (int*)carve((size_t)(n + 1) * 4);
    int*   blk_sums = (int*)carve((size_t)256 * 4);
    float* dinv     = (float*)carve((size_t)n * 4);
    int*   epos     = (int*)carve((size_t)e * 4);
    unsigned short* W1t = (unsigned short*)carve((size_t)FDIM * HDIM * 2);
    unsigned short* W2t = (unsigned short*)carve((size_t)HDIM * HDIM * 2);
    int2*  csr      = (int2*)carve((size_t)e * 8);
    unsigned short* P = (unsigned short*)carve((size_t)n * HDIM * 2);
    unsigned char*  Q = (unsigned char*)carve((size_t)n * HDIM);
    float* pool     = (float*)carve((size_t)GG * HDIM * 4);
    unsigned short* x_bf = P;                       // [N,128] bf16
    unsigned short* a0b  = P + (size_t)n * FDIM;    // [N,128] bf16
    unsigned short* a1b  = P;                       // [N,256] bf16 (x_bf/a0b dead)
    unsigned char*  h1f8 = Q;                       // [N,256] fp8 e4m3
    (void)ws_size; (void)n_in; (void)in_sizes; (void)out_size;

    // cast x + transpose-cast W1,W2 + zero deg/pool, one dispatch (must precede hist)
    cast_all<<<(CAST_TOTAL + 255) / 256, 256, 0, stream>>>(
        x, x_bf, W1, W1t, W2, W2t, deg_i, pool);
    hist_kernel<<<1024, 256, 0, stream>>>(e_dst, deg_i, epos, e);
    scan_part<<<SCAN_NB, 256, 0, stream>>>(deg_i, row_off, blk_sums, dinv, n);
    scan_sums<<<1, 256, 0, stream>>>(blk_sums, SCAN_NB);
    scan_add<<<SCAN_NB, 256, 0, stream>>>(row_off, blk_sums, n, e);
    scatter_kernel<<<1024, 256, 0, stream>>>(e_src, e_dst, row_off, epos, dinv, csr, e);

    dim3 gemm_grid((n + 127) / 128, 2);
    // L1: a0 = agg(x_bf) bf16; h1f8 = fp8(relu(a0 @ W1 + b1))
    gcn_agg128_bf16<<<(n + 3) / 4, 256, 0, stream>>>(x_bf, row_off, csr, dinv, a0b, n);
    gemm1_mfma_bias_relu<<<gemm_grid, 512, 0, stream>>>(a0b, W1t, b1, h1f8, n);
    // L2: a1 = agg(h1f8) bf16; pool += segsum(relu(a1 @ W2 + b2))
    gcn_agg256_fp8<<<(n + 3) / 4, 256, 0, stream>>>(h1f8, row_off, csr, dinv, a1b, n);
    gemm2_pool<<<gemm_grid, 512, 0, stream>>>(a1b, W2t, b2, batch, pool, n);
    // head
    head_kernel<<<GG, 256, 0, stream>>>(pool, batch, num_atoms, W3, b3, W4, b4, out, n);
}

// Round 12
// 287.400 us; speedup vs baseline: 1.0449x; 1.0449x over previous
//
#include <hip/hip_runtime.h>
#include <hip/hip_bf16.h>
#include <hip/hip_fp8.h>

// GNN: 2-layer GCN (N=50000, E=800000, F=128, H=256) + mean-pool (G=512) + MLP head (257->32->4)
// Key identity: segment_sum((xW)[src]*norm) == (segment_sum(x[src]*norm)) @ W  (GCN agg is linear)
//   prep:  cast_all (x->bf16, W transpose, zero deg/pool) -> hist(+epos) -> scan -> scatter
//   L1: agg128 -> a0; h1 = relu(a0 @ W1 + b1) -> FP8 e4m3   [MFMA, 128x128 dbuf tiles]
//   L2: agg256_fp8(h1) -> a1 bf16; gemm2_pool: relu(a1 @ W2 + b2) pooled into pool[G,256]
//   head: per-graph block: mean + 257->32->4 MLP
// R8/R9: agg at 8-XCD compulsory BYTES floor. R11/R13: sliced agg abandoned. R15: agg+GEMM
//   fusion refuted (TLP loss). R16: atomic-free scatter (348->322). R17: fp8 h1 table
//   (agg256 58.7->~33us, 322->297, absmax UNCHANGED).
// R18: occupancy 25->47%, dbuf -> gemm2_pool dur INVARIANT (47.5->48.0us, MfmaUtil 4.6%):
//   not latency/compute/BW-bound. Shared unchanged part = epilogue's 3.2M device-scope
//   fp32 atomics into 512KB pool => atomic-serialization-bound.
// R19: per-graph LDS reduction epilogue: block spans ngr = batch[last]-batch[first]+1
//   graphs (~2-3, sorted batch); reduce into LDS part[ngr][128] (LDS atomics), then emit
//   ngr*128 global atomics per block. 3.2M -> ~250K device atomics (16x).

#define NN 50000
#define EE 800000
#define FDIM 128
#define HDIM 256
#define GG 512
#define SCAN_NB ((NN + 255) / 256)

typedef __attribute__((ext_vector_type(8))) short short8;     // 8 bf16 = 4 VGPRs (MFMA A/B frag)
typedef __attribute__((ext_vector_type(4))) float floatx4;    // MFMA C/D frag
typedef __attribute__((ext_vector_type(2))) float floatx2;

__device__ __forceinline__ unsigned short f2bf(float f) {   // RNE
    unsigned u = __float_as_uint(f);
    return (unsigned short)((u + 0x7FFF + ((u >> 16) & 1)) >> 16);
}
__device__ __forceinline__ float bflo(unsigned v) { return __uint_as_float(v << 16); }
__device__ __forceinline__ float bfhi(unsigned v) { return __uint_as_float(v & 0xFFFF0000u); }

// fp8 e4m3 (OCP on gfx950) encode/decode via HW cvt; fallback to hip_fp8 type.
__device__ __forceinline__ unsigned char enc8(float v) {
#if defined(__has_builtin) && __has_builtin(__builtin_amdgcn_cvt_pk_fp8_f32)
    return (unsigned char)(__builtin_amdgcn_cvt_pk_fp8_f32(v, v, 0, false) & 0xFF);
#else
    __hip_fp8_e4m3 q(v);
    return (unsigned char)q.__x;
#endif
}
__device__ __forceinline__ void dec4(int d, float* f) {   // 4 fp8 bytes -> 4 floats
#if defined(__has_builtin) && __has_builtin(__builtin_amdgcn_cvt_pk_f32_fp8)
    floatx2 lo = __builtin_amdgcn_cvt_pk_f32_fp8(d, false);
    floatx2 hi = __builtin_amdgcn_cvt_pk_f32_fp8(d, true);
    f[0] = lo.x; f[1] = lo.y; f[2] = hi.x; f[3] = hi.y;
#else
    unsigned u = (unsigned)d;
    #pragma unroll
    for (int i = 0; i < 4; ++i) {
        __hip_fp8_e4m3 t; t.__x = (__hip_fp8_storage_t)((u >> (8 * i)) & 0xFF);
        f[i] = (float)t;
    }
#endif
}

// async global->LDS, 16B per lane. lds ptr must be wave-uniform (HW adds lane*16).
__device__ __forceinline__ void gload16(const void* g, void* l) {
    __builtin_amdgcn_global_load_lds((const __attribute__((address_space(1))) void*)g,
                                     (__attribute__((address_space(3))) void*)l, 16, 0, 0);
}

// ---------------- prep kernels ----------------

// hist + per-edge ordinal: epos[i] = old count of dst[i]. Scatter then needs no atomics.
__global__ void hist_kernel(const int* __restrict__ dst, int* __restrict__ deg,
                            int* __restrict__ epos, int e) {
    int i = blockIdx.x * blockDim.x + threadIdx.x;
    int stride = gridDim.x * blockDim.x;
    for (; i < e; i += stride) epos[i] = atomicAdd(&deg[dst[i]], 1);
}

__global__ __launch_bounds__(256) void scan_part(const int* __restrict__ deg,
                                                 int* __restrict__ row_off,
                                                 int* __restrict__ blk_sums,
                                                 float* __restrict__ dinv, int n) {
    __shared__ int s[256];
    int tid = threadIdx.x;
    int i = blockIdx.x * 256 + tid;
    int v = (i < n) ? deg[i] : 0;
    if (i < n) dinv[i] = rsqrtf((float)v + 1.0f);
    s[tid] = v;
    __syncthreads();
    #pragma unroll
    for (int off = 1; off < 256; off <<= 1) {
        int t = (tid >= off) ? s[tid - off] : 0;
        __syncthreads();
        s[tid] += t;
        __syncthreads();
    }
    if (i < n) row_off[i] = s[tid] - v;
    if (tid == 255) blk_sums[blockIdx.x] = s[255];
}

__global__ __launch_bounds__(256) void scan_sums(int* __restrict__ blk_sums, int nb) {
    __shared__ int s[256];
    int tid = threadIdx.x;
    int v = (tid < nb) ? blk_sums[tid] : 0;
    s[tid] = v;
    __syncthreads();
    #pragma unroll
    for (int off = 1; off < 256; off <<= 1) {
        int t = (tid >= off) ? s[tid - off] : 0;
        __syncthreads();
        s[tid] += t;
        __syncthreads();
    }
    if (tid < nb) blk_sums[tid] = s[tid] - v;
}

__global__ __launch_bounds__(256) void scan_add(int* __restrict__ row_off,
                                                const int* __restrict__ blk_sums,
                                                int n, int e) {
    int i = blockIdx.x * 256 + threadIdx.x;
    if (i < n) row_off[i] += blk_sums[blockIdx.x];
    if (i == 0) row_off[n] = e;
}

// atomic-free scatter: position = row_off[dst] + epos (ordinal captured in hist)
__global__ void scatter_kernel(const int* __restrict__ src, const int* __restrict__ dst,
                               const int* __restrict__ row_off, const int* __restrict__ epos,
                               const float* __restrict__ dinv,
                               int2* __restrict__ csr, int e) {
    int i = blockIdx.x * blockDim.x + threadIdx.x;
    int stride = gridDim.x * blockDim.x;
    for (; i < e; i += stride) {
        int s = src[i], d = dst[i];
        int pos = row_off[d] + epos[i];
        csr[pos] = make_int2(s, __float_as_int(dinv[s] * dinv[d]));
    }
}

// merged: x fp32->bf16 cast + W1/W2 transpose-cast + zero deg/pool. One dispatch.
#define XCHUNKS (NN * FDIM / 4)            // 1,600,000 float4 groups
#define CAST_TOTAL (XCHUNKS + FDIM * HDIM + HDIM * HDIM + NN / 4 + GG * HDIM / 4)
__global__ __launch_bounds__(256) void cast_all(const float* __restrict__ x,
                                                unsigned short* __restrict__ x_bf,
                                                const float* __restrict__ W1,
                                                unsigned short* __restrict__ W1t,
                                                const float* __restrict__ W2,
                                                unsigned short* __restrict__ W2t,
                                                int* __restrict__ deg,
                                                float* __restrict__ pool) {
    int idx = blockIdx.x * 256 + threadIdx.x;
    if (idx < XCHUNKS) {
        int i = idx * 4;
        float4 v = *(const float4*)&x[i];
        ushort4 o;
        o.x = f2bf(v.x); o.y = f2bf(v.y); o.z = f2bf(v.z); o.w = f2bf(v.w);
        *(ushort4*)&x_bf[i] = o;
        return;
    }
    int r = idx - XCHUNKS;
    if (r < FDIM * HDIM) {               // W1t[n][k] = bf16(W1[k][n]), K=128, Nc=256
        int nn = r / FDIM, k = r - nn * FDIM;
        W1t[r] = f2bf(W1[(size_t)k * HDIM + nn]);
        return;
    }
    r -= FDIM * HDIM;
    if (r < HDIM * HDIM) {               // W2t[n][k] = bf16(W2[k][n]), K=256, Nc=256
        int nn = r / HDIM, k = r - nn * HDIM;
        W2t[r] = f2bf(W2[(size_t)k * HDIM + nn]);
        return;
    }
    r -= HDIM * HDIM;
    if (r < NN / 4) {                    // zero deg (50000 % 4 == 0)
        int4 z = {0, 0, 0, 0};
        *(int4*)&deg[r * 4] = z;
        return;
    }
    r -= NN / 4;
    if (r < GG * HDIM / 4) {             // zero pool
        float4 z = {0.f, 0.f, 0.f, 0.f};
        *(float4*)&pool[r * 4] = z;
    }
}

// ---------------- GCN aggregation ----------------
// out[d] = sum_e in[src_e]*w_e + in[d]*dinv[d]^2
// wave-per-node, dwordx4 gathers (16B/lane). Wave split across edges.
// At the 8-XCD compulsory-traffic floor (FETCH = 8 x table bytes).
// NOTE: macro param must NOT be named 'w' (collides with .w member access).

#define FMA8(v, wgt) do { unsigned _u; \
    _u = (unsigned)(v).x; acc0 = fmaf(bflo(_u), (wgt), acc0); acc1 = fmaf(bfhi(_u), (wgt), acc1); \
    _u = (unsigned)(v).y; acc2 = fmaf(bflo(_u), (wgt), acc2); acc3 = fmaf(bfhi(_u), (wgt), acc3); \
    _u = (unsigned)(v).z; acc4 = fmaf(bflo(_u), (wgt), acc4); acc5 = fmaf(bfhi(_u), (wgt), acc5); \
    _u = (unsigned)(v).w; acc6 = fmaf(bflo(_u), (wgt), acc6); acc7 = fmaf(bfhi(_u), (wgt), acc7); } while (0)

__device__ __forceinline__ void fma16(const int4& g, float wgt, float* acc) {
    float f[16];
    dec4(g.x, f); dec4(g.y, f + 4); dec4(g.z, f + 8); dec4(g.w, f + 12);
    #pragma unroll
    for (int i = 0; i < 16; ++i) acc[i] = fmaf(f[i], wgt, acc[i]);
}

// L2 aggregation over the fp8 h1 table: row = 256 fp8 = 256B; 16 lanes x 16B per row;
// sub = lane>>4 -> 4 edge slots; 2 int4 gathers (8 edges) in flight. Output a1 bf16.
__global__ __launch_bounds__(256) void gcn_agg256_fp8(const unsigned char* __restrict__ in,
                                                      const int* __restrict__ row_off,
                                                      const int2* __restrict__ csr,
                                                      const float* __restrict__ dinv,
                                                      unsigned short* __restrict__ out, int n) {
    int wave = threadIdx.x >> 6;
    int lane = threadIdx.x & 63;
    int node = blockIdx.x * 4 + wave;
    if (node >= n) return;
    int sub = lane >> 4;          // edge slot 0..3
    int fl  = lane & 15;          // 16B chunk within 256B row
    float di = dinv[node];
    float w0 = (sub == 0) ? di * di : 0.f;

    float acc[16];
    {   // self term
        int4 sv = *(const int4*)&in[(size_t)node * 256 + fl * 16];
        float f[16];
        dec4(sv.x, f); dec4(sv.y, f + 4); dec4(sv.z, f + 8); dec4(sv.w, f + 12);
        #pragma unroll
        for (int i = 0; i < 16; ++i) acc[i] = f[i] * w0;
    }

    int beg = __builtin_amdgcn_readfirstlane(row_off[node]);
    int end = __builtin_amdgcn_readfirstlane(row_off[node + 1]);
    int cnt = end - beg;
    if (cnt > 0) {
        int nIter = (cnt + 7) >> 3;                    // 8 edges / iter (2 gathers)
        int base = beg;
        int last = end - 1;
        int i0 = base + sub, i1 = base + 4 + sub;
        int2 c0 = csr[i0 < end ? i0 : last];
        int2 c1 = csr[i1 < end ? i1 : last];
        for (int it = 0; it < nIter; ++it) {
            int4 g0 = *(const int4*)&in[(size_t)c0.x * 256 + fl * 16];
            int4 g1 = *(const int4*)&in[(size_t)c1.x * 256 + fl * 16];
            float we0 = (base + sub < end) ? __int_as_float(c0.y) : 0.f;
            float we1 = (base + 4 + sub < end) ? __int_as_float(c1.y) : 0.f;
            int nb = base + 8;
            int j0 = nb + sub, j1 = nb + 4 + sub;
            int2 n0 = csr[j0 < end ? j0 : last];
            int2 n1 = csr[j1 < end ? j1 : last];
            fma16(g0, we0, acc); fma16(g1, we1, acc);
            c0 = n0; c1 = n1; base = nb;
        }
    }
    // combine 4 edge-slots (lanes sharing fl differ in bits 4..5)
    #pragma unroll
    for (int i = 0; i < 16; ++i) {
        acc[i] += __shfl_xor(acc[i], 16);
        acc[i] += __shfl_xor(acc[i], 32);
    }
    if (sub == 0) {
        int4 o0, o1;
        o0.x = (int)((unsigned)f2bf(acc[0])  | ((unsigned)f2bf(acc[1])  << 16));
        o0.y = (int)((unsigned)f2bf(acc[2])  | ((unsigned)f2bf(acc[3])  << 16));
        o0.z = (int)((unsigned)f2bf(acc[4])  | ((unsigned)f2bf(acc[5])  << 16));
        o0.w = (int)((unsigned)f2bf(acc[6])  | ((unsigned)f2bf(acc[7])  << 16));
        o1.x = (int)((unsigned)f2bf(acc[8])  | ((unsigned)f2bf(acc[9])  << 16));
        o1.y = (int)((unsigned)f2bf(acc[10]) | ((unsigned)f2bf(acc[11]) << 16));
        o1.z = (int)((unsigned)f2bf(acc[12]) | ((unsigned)f2bf(acc[13]) << 16));
        o1.w = (int)((unsigned)f2bf(acc[14]) | ((unsigned)f2bf(acc[15]) << 16));
        *(int4*)&out[(size_t)node * 256 + fl * 16] = o0;
        *(int4*)&out[(size_t)node * 256 + fl * 16 + 8] = o1;
    }
}

__global__ __launch_bounds__(256) void gcn_agg128_bf16(const unsigned short* __restrict__ in,
                                                       const int* __restrict__ row_off,
                                                       const int2* __restrict__ csr,
                                                       const float* __restrict__ dinv,
                                                       unsigned short* __restrict__ out, int n) {
    int wave = threadIdx.x >> 6;
    int lane = threadIdx.x & 63;
    int node = blockIdx.x * 4 + wave;
    if (node >= n) return;
    int sub = lane >> 4;          // edge slot 0..3
    int fl  = lane & 15;          // 16B feature chunk within row
    float di = dinv[node];
    float w0 = (sub == 0) ? di * di : 0.f;

    float acc0, acc1, acc2, acc3, acc4, acc5, acc6, acc7;
    {   // self term
        int4 sv = *(const int4*)&in[(size_t)node * 128 + fl * 8];
        unsigned _u;
        _u = (unsigned)sv.x; acc0 = bflo(_u) * w0; acc1 = bfhi(_u) * w0;
        _u = (unsigned)sv.y; acc2 = bflo(_u) * w0; acc3 = bfhi(_u) * w0;
        _u = (unsigned)sv.z; acc4 = bflo(_u) * w0; acc5 = bfhi(_u) * w0;
        _u = (unsigned)sv.w; acc6 = bflo(_u) * w0; acc7 = bfhi(_u) * w0;
    }

    int beg = __builtin_amdgcn_readfirstlane(row_off[node]);
    int end = __builtin_amdgcn_readfirstlane(row_off[node + 1]);
    int cnt = end - beg;
    if (cnt > 0) {
        int nIter = (cnt + 7) >> 3;                    // 8 edges / iter (2 gathers)
        int base = beg;
        int last = end - 1;
        int i0 = base + sub, i1 = base + 4 + sub;
        int2 c0 = csr[i0 < end ? i0 : last];
        int2 c1 = csr[i1 < end ? i1 : last];
        for (int it = 0; it < nIter; ++it) {
            int4 g0 = *(const int4*)&in[(size_t)c0.x * 128 + fl * 8];
            int4 g1 = *(const int4*)&in[(size_t)c1.x * 128 + fl * 8];
            float we0 = (base + sub < end) ? __int_as_float(c0.y) : 0.f;
            float we1 = (base + 4 + sub < end) ? __int_as_float(c1.y) : 0.f;
            int nb = base + 8;
            int j0 = nb + sub, j1 = nb + 4 + sub;
            int2 n0 = csr[j0 < end ? j0 : last];
            int2 n1 = csr[j1 < end ? j1 : last];
            FMA8(g0, we0); FMA8(g1, we1);
            c0 = n0; c1 = n1; base = nb;
        }
    }
    // combine 4 edge-slots
    acc0 += __shfl_xor(acc0, 16); acc1 += __shfl_xor(acc1, 16);
    acc2 += __shfl_xor(acc2, 16); acc3 += __shfl_xor(acc3, 16);
    acc4 += __shfl_xor(acc4, 16); acc5 += __shfl_xor(acc5, 16);
    acc6 += __shfl_xor(acc6, 16); acc7 += __shfl_xor(acc7, 16);
    acc0 += __shfl_xor(acc0, 32); acc1 += __shfl_xor(acc1, 32);
    acc2 += __shfl_xor(acc2, 32); acc3 += __shfl_xor(acc3, 32);
    acc4 += __shfl_xor(acc4, 32); acc5 += __shfl_xor(acc5, 32);
    acc6 += __shfl_xor(acc6, 32); acc7 += __shfl_xor(acc7, 32);
    if (sub == 0) {
        int4 o;
        o.x = (int)((unsigned)f2bf(acc0) | ((unsigned)f2bf(acc1) << 16));
        o.y = (int)((unsigned)f2bf(acc2) | ((unsigned)f2bf(acc3) << 16));
        o.z = (int)((unsigned)f2bf(acc4) | ((unsigned)f2bf(acc5) << 16));
        o.w = (int)((unsigned)f2bf(acc6) | ((unsigned)f2bf(acc7) << 16));
        *(int4*)&out[(size_t)node * 128 + fl * 8] = o;
    }
}

// ---------------- bf16 MFMA GEMM, 128x128 tiles, dbuf, 8 waves (2x4 of 64x32) ----------------
// grid (ceil(M/128), 2): bn = blockIdx.y*128. Per K-step each thread stages one 16B
// A-chunk + one 16B B-chunk via global_load_lds into LINEAR LDS (LDT=32). Double-buffered:
// STAGE(next) issued BEFORE compute(cur); single __syncthreads per step (drains vmcnt).
// Wave tile 64x32: acc[4][2]. Verified frag layouts (learn_hip m89/m91/m120).

__global__ __launch_bounds__(512, 2) void gemm1_mfma_bias_relu(
        const unsigned short* __restrict__ A,    // [M][128] bf16
        const unsigned short* __restrict__ Bt,   // [256][128] bf16
        const float* __restrict__ bias,          // [256] fp32
        unsigned char* __restrict__ C, int M) {  // [M][256] fp8 e4m3
    constexpr int K = FDIM, Nc = HDIM, LDT = 32;
    __shared__ unsigned short As[2][128 * LDT];  // 8KB per buffer
    __shared__ unsigned short Bs[2][128 * LDT];
    int tid = threadIdx.x;
    int lane = tid & 63, wave = tid >> 6;
    int wm = (wave >> 2) * 64;                   // 0 | 64
    int wn2 = (wave & 3) * 32;                   // 0,32,64,96
    int bm = blockIdx.x * 128;
    int bn = blockIdx.y * 128;
    int l15 = lane & 15, quad = lane >> 4;
    int srow = tid >> 2, sq = (tid & 3) * 8;     // staging: row 0..127, k-subchunk

    floatx4 zero = {0.f, 0.f, 0.f, 0.f};
    floatx4 acc[4][2];
    #pragma unroll
    for (int s = 0; s < 4; ++s)
        #pragma unroll
        for (int t = 0; t < 2; ++t) acc[s][t] = zero;

    // prologue: stage k0=0 into buf 0
    gload16(&A[(size_t)(bm + srow) * K + sq], &As[0][wave * 512]);
    gload16(&Bt[(size_t)(bn + srow) * K + sq], &Bs[0][wave * 512]);
    __syncthreads();
    int cur = 0;
    for (int k0 = 0; k0 < K; k0 += 32) {
        if (k0 + 32 < K) {   // stage next K-step into the other buffer
            gload16(&A[(size_t)(bm + srow) * K + k0 + 32 + sq], &As[cur ^ 1][wave * 512]);
            gload16(&Bt[(size_t)(bn + srow) * K + k0 + 32 + sq], &Bs[cur ^ 1][wave * 512]);
        }
        short8 af[4], bf[2];
        #pragma unroll
        for (int s = 0; s < 4; ++s)
            af[s] = *(const short8*)&As[cur][(wm + s * 16 + l15) * LDT + quad * 8];
        #pragma unroll
        for (int t = 0; t < 2; ++t)
            bf[t] = *(const short8*)&Bs[cur][(wn2 + t * 16 + l15) * LDT + quad * 8];
        #pragma unroll
        for (int s = 0; s < 4; ++s)
            #pragma unroll
            for (int t = 0; t < 2; ++t)
                acc[s][t] = __builtin_amdgcn_mfma_f32_16x16x32_bf16(af[s], bf[t], acc[s][t], 0, 0, 0);
        __syncthreads();                          // drains stage vmcnt + LDS reads
        cur ^= 1;
    }
    #pragma unroll
    for (int s = 0; s < 4; ++s) {
        int row0 = bm + wm + s * 16 + quad * 4;
        #pragma unroll
        for (int t = 0; t < 2; ++t) {
            int col = bn + wn2 + t * 16 + l15;
            float bb = bias[col];
            #pragma unroll
            for (int r = 0; r < 4; ++r) {
                int row = row0 + r;
                if (row < M)
                    C[(size_t)row * Nc + col] = enc8(fmaxf(acc[s][t][r] + bb, 0.f));
            }
        }
    }
}

// GEMM2 fused with mean-pool numerator. R19 epilogue: per-graph LDS reduction
// (part[ngr][128] via LDS atomics, reusing staging LDS), then ngr*128 global atomics
// per block instead of 4096. Fallback to direct atomics if ngr > 8 (never at ~98
// nodes/graph).
__global__ __launch_bounds__(512, 2) void gemm2_pool(
        const unsigned short* __restrict__ A,    // [M][256] bf16 (a1b)
        const unsigned short* __restrict__ Bt,   // [256][256] bf16
        const float* __restrict__ bias,          // [256] fp32
        const int* __restrict__ batch,           // [M] sorted graph ids
        float* __restrict__ pool, int M) {       // [G][256] fp32, pre-zeroed
    constexpr int K = HDIM, Nc = HDIM, LDT = 32;
    constexpr int NGR_CAP = 8;
    __shared__ unsigned short As[2][128 * LDT];
    __shared__ unsigned short Bs[2][128 * LDT];
    int tid = threadIdx.x;
    int lane = tid & 63, wave = tid >> 6;
    int wm = (wave >> 2) * 64;
    int wn2 = (wave & 3) * 32;
    int bm = blockIdx.x * 128;
    int bn = blockIdx.y * 128;
    int l15 = lane & 15, quad = lane >> 4;
    int srow = tid >> 2, sq = (tid & 3) * 8;

    floatx4 zero = {0.f, 0.f, 0.f, 0.f};
    floatx4 acc[4][2];
    #pragma unroll
    for (int s = 0; s < 4; ++s)
        #pragma unroll
        for (int t = 0; t < 2; ++t) acc[s][t] = zero;

    gload16(&A[(size_t)(bm + srow) * K + sq], &As[0][wave * 512]);
    gload16(&Bt[(size_t)(bn + srow) * K + sq], &Bs[0][wave * 512]);
    __syncthreads();
    int cur = 0;
    for (int k0 = 0; k0 < K; k0 += 32) {
        if (k0 + 32 < K) {
            gload16(&A[(size_t)(bm + srow) * K + k0 + 32 + sq], &As[cur ^ 1][wave * 512]);
            gload16(&Bt[(size_t)(bn + srow) * K + k0 + 32 + sq], &Bs[cur ^ 1][wave * 512]);
        }
        short8 af[4], bf[2];
        #pragma unroll
        for (int s = 0; s < 4; ++s)
            af[s] = *(const short8*)&As[cur][(wm + s * 16 + l15) * LDT + quad * 8];
        #pragma unroll
        for (int t = 0; t < 2; ++t)
            bf[t] = *(const short8*)&Bs[cur][(wn2 + t * 16 + l15) * LDT + quad * 8];
        #pragma unroll
        for (int s = 0; s < 4; ++s)
            #pragma unroll
            for (int t = 0; t < 2; ++t)
                acc[s][t] = __builtin_amdgcn_mfma_f32_16x16x32_bf16(af[s], bf[t], acc[s][t], 0, 0, 0);
        __syncthreads();
        cur ^= 1;
    }
    // ---- R19 epilogue ----
    // (loop ended with barrier -> LDS reads done; staging LDS reusable as fp32 partials)
    float* part = (float*)&As[0][0];            // NGR_CAP*128 floats = 4KB
    int lastRow = min(bm + 127, M - 1);
    int gfirst = batch[bm];
    int glast = batch[lastRow];
    int ngr = glast - gfirst + 1;
    if (ngr <= NGR_CAP) {
        for (int i = tid; i < ngr * 128; i += 512) part[i] = 0.f;
        __syncthreads();
        #pragma unroll
        for (int s = 0; s < 4; ++s) {
            int row0 = bm + wm + s * 16 + quad * 4;
            if (row0 >= M) continue;
            int gA = batch[row0];
            bool full = (row0 + 3 < M);
            bool same = full && (batch[row0 + 3] == gA);
            #pragma unroll
            for (int t = 0; t < 2; ++t) {
                int colL = wn2 + t * 16 + l15;
                float bb = bias[bn + colL];
                if (same) {
                    float v = fmaxf(acc[s][t][0] + bb, 0.f) + fmaxf(acc[s][t][1] + bb, 0.f)
                            + fmaxf(acc[s][t][2] + bb, 0.f) + fmaxf(acc[s][t][3] + bb, 0.f);
                    atomicAdd(&part[(gA - gfirst) * 128 + colL], v);
                } else {
                    #pragma unroll
                    for (int r = 0; r < 4; ++r) {
                        int row = row0 + r;
                        if (row < M) {
                            float v = fmaxf(acc[s][t][r] + bb, 0.f);
                            atomicAdd(&part[(batch[row] - gfirst) * 128 + colL], v);
                        }
                    }
                }
            }
        }
        __syncthreads();
        for (int i = tid; i < ngr * 128; i += 512) {
            float v = part[i];
            if (v != 0.f)
                atomicAdd(&pool[(size_t)(gfirst + (i >> 7)) * Nc + bn + (i & 127)], v);
        }
    } else {
        // fallback: direct atomics (unreachable for ~98-node graphs)
        #pragma unroll
        for (int s = 0; s < 4; ++s) {
            int row0 = bm + wm + s * 16 + quad * 4;
            if (row0 >= M) continue;
            #pragma unroll
            for (int t = 0; t < 2; ++t) {
                int col = bn + wn2 + t * 16 + l15;
                float bb = bias[col];
                #pragma unroll
                for (int r = 0; r < 4; ++r) {
                    int row = row0 + r;
                    if (row < M) {
                        float v = fmaxf(acc[s][t][r] + bb, 0.f);
                        atomicAdd(&pool[(size_t)batch[row] * Nc + col], v);
                    }
                }
            }
        }
    }
}

// ---------------- head: one block per graph, reads pooled sums ----------------

__device__ __forceinline__ int lower_bound_i(const int* __restrict__ a, int n, int v) {
    int lo = 0, hi = n;
    while (lo < hi) {
        int mid = (lo + hi) >> 1;
        if (a[mid] < v) lo = mid + 1; else hi = mid;
    }
    return lo;
}

__global__ __launch_bounds__(256) void head_kernel(const float* __restrict__ pool,
                                                   const int* __restrict__ batch,
                                                   const float* __restrict__ num_atoms,
                                                   const float* __restrict__ W3, const float* __restrict__ b3,
                                                   const float* __restrict__ W4, const float* __restrict__ b4,
                                                   float* __restrict__ out, int n) {
    int g = blockIdx.x;
    int tid = threadIdx.x;
    __shared__ int s_lo, s_hi;
    if (tid == 0) {
        s_lo = lower_bound_i(batch, n, g);
        s_hi = lower_bound_i(batch, n, g + 1);
    }
    __syncthreads();
    float cnt = (float)(s_hi - s_lo);

    __shared__ float zin[HDIM + 1];
    __shared__ float z[32];
    zin[tid] = pool[(size_t)g * HDIM + tid] / fmaxf(cnt, 1.0f);
    if (tid == 0) zin[HDIM] = num_atoms[g];
    __syncthreads();
    if (tid < 32) {
        float a = b3[tid];
        for (int k = 0; k < HDIM + 1; ++k) a = fmaf(zin[k], W3[k * 32 + tid], a);
        z[tid] = fmaxf(a, 0.f);
    }
    __syncthreads();
    if (tid < 4) {
        float a = b4[tid];
        #pragma unroll
        for (int k = 0; k < 32; ++k) a = fmaf(z[k], W4[k * 4 + tid], a);
        out[g * 4 + tid] = a;
    }
}

// ---------------- launch ----------------

extern "C" void kernel_launch(void* const* d_in, const int* in_sizes, int n_in,
                              void* d_out, int out_size, void* d_ws, size_t ws_size,
                              hipStream_t stream) {
    const float* x         = (const float*)d_in[0];
    const int*   edge_idx  = (const int*)d_in[1];
    const int*   batch     = (const int*)d_in[2];
    const float* num_atoms = (const float*)d_in[3];
    const float* W1 = (const float*)d_in[4];
    const float* b1 = (const float*)d_in[5];
    const float* W2 = (const float*)d_in[6];
    const float* b2 = (const float*)d_in[7];
    const float* W3 = (const float*)d_in[8];
    const float* b3 = (const float*)d_in[9];
    const float* W4 = (const float*)d_in[10];
    const float* b4 = (const float*)d_in[11];
    float* out = (float*)d_out;

    const int n = NN, e = EE;
    const int* e_src = edge_idx;
    const int* e_dst = edge_idx + e;

    // workspace (256B aligned). Lifetime aliasing:
    //   P (25.6MB): {x_bf [N,128]bf16 ; a0b [N,128]bf16} live through gemm1,
    //               then whole P reused as a1b [N,256]bf16 (agg256 out).
    //   Q (12.8MB): h1f8 [N,256]fp8 (gemm1 out, dead after agg256). Also absorbs GEMM
    //               staging over-reads past row M.
    //   pool (512KB): [G,256] fp32 pooled sums (gemm2_pool out -> head).
    char* ws = (char*)d_ws;
    size_t off = 0;
    auto carve = [&](size_t bytes) -> void* {
        void* p = ws + off;
        off = (off + bytes + 255) & ~(size_t)255;
        return p;
    };
    int*   deg_i    = (int*)carve((size_t)n * 4);
    int*   row_off  = (int*)carve((size_t)(n + 1) * 4);
    int*   blk_sums = (int*)carve((size_t)256 * 4);
    float* dinv     = (float*)carve((size_t)n * 4);
    int*   epos     = (int*)carve((size_t)e * 4);
    unsigned short* W1t = (unsigned short*)carve((size_t)FDIM * HDIM * 2);
    unsigned short* W2t = (unsigned short*)carve((size_t)HDIM * HDIM * 2);
    int2*  csr      = (int2*)carve((size_t)e * 8);
    unsigned short* P = (unsigned short*)carve((size_t)n * HDIM * 2);
    unsigned char*  Q = (unsigned char*)carve((size_t)n * HDIM);
    float* pool     = (float*)carve((size_t)GG * HDIM * 4);
    unsigned short* x_bf = P;                       // [N,128] bf16
    unsigned short* a0b  = P + (size_t)n * FDIM;    // [N,128] bf16
    unsigned short* a1b  = P;                       // [N,256] bf16 (x_bf/a0b dead)
    unsigned char*  h1f8 = Q;                       // [N,256] fp8 e4m3
    (void)ws_size; (void)n_in; (void)in_sizes; (void)out_size;

    // cast x + transpose-cast W1,W2 + zero deg/pool, one dispatch (must precede hist)
    cast_all<<<(CAST_TOTAL + 255) / 256, 256, 0, stream>>>(
        x, x_bf, W1, W1t, W2, W2t, deg_i, pool);
    hist_kernel<<<1024, 256, 0, stream>>>(e_dst, deg_i, epos, e);
    scan_part<<<SCAN_NB, 256, 0, stream>>>(deg_i, row_off, blk_sums, dinv, n);
    scan_sums<<<1, 256, 0, stream>>>(blk_sums, SCAN_NB);
    scan_add<<<SCAN_NB, 256, 0, stream>>>(row_off, blk_sums, n, e);
    scatter_kernel<<<1024, 256, 0, stream>>>(e_src, e_dst, row_off, epos, dinv, csr, e);

    dim3 gemm_grid((n + 127) / 128, 2);
    // L1: a0 = agg(x_bf) bf16; h1f8 = fp8(relu(a0 @ W1 + b1))
    gcn_agg128_bf16<<<(n + 3) / 4, 256, 0, stream>>>(x_bf, row_off, csr, dinv, a0b, n);
    gemm1_mfma_bias_relu<<<gemm_grid, 512, 0, stream>>>(a0b, W1t, b1, h1f8, n);
    // L2: a1 = agg(h1f8) bf16; pool += segsum(relu(a1 @ W2 + b2))
    gcn_agg256_fp8<<<(n + 3) / 4, 256, 0, stream>>>(h1f8, row_off, csr, dinv, a1b, n);
    gemm2_pool<<<gemm_grid, 512, 0, stream>>>(a1b, W2t, b2, batch, pool, n);
    // head
    head_kernel<<<GG, 256, 0, stream>>>(pool, batch, num_atoms, W3, b3, W4, b4, out, n);
}

// Round 13
// 286.565 us; speedup vs baseline: 1.0479x; 1.0029x over previous
//
#include <hip/hip_runtime.h>
#include <hip/hip_bf16.h>
#include <hip/hip_fp8.h>

// GNN: 2-layer GCN (N=50000, E=800000, F=128, H=256) + mean-pool (G=512) + MLP head (257->32->4)
// Key identity: segment_sum((xW)[src]*norm) == (segment_sum(x[src]*norm)) @ W  (GCN agg is linear)
//   prep:  cast_all (x->FP8, W transpose, zero deg/pool) -> hist(+epos) -> scan -> scatter
//   L1: agg128_fp8(x_f8) -> a0 bf16; h1 = relu(a0 @ W1 + b1) -> FP8 e4m3  [MFMA dbuf tiles]
//   L2: agg256_fp8(h1) -> a1 bf16; gemm2_pool: relu(a1 @ W2 + b2) pooled into pool[G,256]
//   head: per-graph block: mean + 257->32->4 MLP
// R8/R9: agg at 8-XCD compulsory BYTES floor (FETCH = 8 x table). R11/R13: sliced agg
//   abandoned. R15: agg+GEMM fusion refuted (TLP loss). R16: atomic-free scatter (348->322).
// R17: fp8 h1 table (agg256 58.7->~33us, 322->297, absmax UNCHANGED).
// R18: occupancy 25->47% + dbuf -> gemm2_pool INVARIANT => atomic-serialization-bound.
// R19: per-graph LDS reduction epilogue (3.2M -> ~250K device atomics; 300->287).
// R20: same bytes-floor lever on x: x table fp8 e4m3 (12.8->6.4MB), agg128 restructured
//   to 8 slots x 8 lanes x 16B with cvt_pk_f32_fp8 decode; a0 stays bf16 (gemm1 untouched).

#define NN 50000
#define EE 800000
#define FDIM 128
#define HDIM 256
#define GG 512
#define SCAN_NB ((NN + 255) / 256)

typedef __attribute__((ext_vector_type(8))) short short8;     // 8 bf16 = 4 VGPRs (MFMA A/B frag)
typedef __attribute__((ext_vector_type(4))) float floatx4;    // MFMA C/D frag
typedef __attribute__((ext_vector_type(2))) float floatx2;

__device__ __forceinline__ unsigned short f2bf(float f) {   // RNE
    unsigned u = __float_as_uint(f);
    return (unsigned short)((u + 0x7FFF + ((u >> 16) & 1)) >> 16);
}
__device__ __forceinline__ float bflo(unsigned v) { return __uint_as_float(v << 16); }
__device__ __forceinline__ float bfhi(unsigned v) { return __uint_as_float(v & 0xFFFF0000u); }

// fp8 e4m3 (OCP on gfx950) encode/decode via HW cvt; fallback to hip_fp8 type.
__device__ __forceinline__ unsigned char enc8(float v) {
#if defined(__has_builtin) && __has_builtin(__builtin_amdgcn_cvt_pk_fp8_f32)
    return (unsigned char)(__builtin_amdgcn_cvt_pk_fp8_f32(v, v, 0, false) & 0xFF);
#else
    __hip_fp8_e4m3 q(v);
    return (unsigned char)q.__x;
#endif
}
__device__ __forceinline__ unsigned pack4_fp8(float a, float b, float c, float d) {
#if defined(__has_builtin) && __has_builtin(__builtin_amdgcn_cvt_pk_fp8_f32)
    unsigned lo = (unsigned)__builtin_amdgcn_cvt_pk_fp8_f32(a, b, 0, false) & 0xFFFFu;
    unsigned hi = (unsigned)__builtin_amdgcn_cvt_pk_fp8_f32(c, d, 0, false) & 0xFFFFu;
    return lo | (hi << 16);
#else
    return (unsigned)enc8(a) | ((unsigned)enc8(b) << 8) |
           ((unsigned)enc8(c) << 16) | ((unsigned)enc8(d) << 24);
#endif
}
__device__ __forceinline__ void dec4(int d, float* f) {   // 4 fp8 bytes -> 4 floats
#if defined(__has_builtin) && __has_builtin(__builtin_amdgcn_cvt_pk_f32_fp8)
    floatx2 lo = __builtin_amdgcn_cvt_pk_f32_fp8(d, false);
    floatx2 hi = __builtin_amdgcn_cvt_pk_f32_fp8(d, true);
    f[0] = lo.x; f[1] = lo.y; f[2] = hi.x; f[3] = hi.y;
#else
    unsigned u = (unsigned)d;
    #pragma unroll
    for (int i = 0; i < 4; ++i) {
        __hip_fp8_e4m3 t; t.__x = (__hip_fp8_storage_t)((u >> (8 * i)) & 0xFF);
        f[i] = (float)t;
    }
#endif
}

// async global->LDS, 16B per lane. lds ptr must be wave-uniform (HW adds lane*16).
__device__ __forceinline__ void gload16(const void* g, void* l) {
    __builtin_amdgcn_global_load_lds((const __attribute__((address_space(1))) void*)g,
                                     (__attribute__((address_space(3))) void*)l, 16, 0, 0);
}

// ---------------- prep kernels ----------------

// hist + per-edge ordinal: epos[i] = old count of dst[i]. Scatter then needs no atomics.
__global__ void hist_kernel(const int* __restrict__ dst, int* __restrict__ deg,
                            int* __restrict__ epos, int e) {
    int i = blockIdx.x * blockDim.x + threadIdx.x;
    int stride = gridDim.x * blockDim.x;
    for (; i < e; i += stride) epos[i] = atomicAdd(&deg[dst[i]], 1);
}

__global__ __launch_bounds__(256) void scan_part(const int* __restrict__ deg,
                                                 int* __restrict__ row_off,
                                                 int* __restrict__ blk_sums,
                                                 float* __restrict__ dinv, int n) {
    __shared__ int s[256];
    int tid = threadIdx.x;
    int i = blockIdx.x * 256 + tid;
    int v = (i < n) ? deg[i] : 0;
    if (i < n) dinv[i] = rsqrtf((float)v + 1.0f);
    s[tid] = v;
    __syncthreads();
    #pragma unroll
    for (int off = 1; off < 256; off <<= 1) {
        int t = (tid >= off) ? s[tid - off] : 0;
        __syncthreads();
        s[tid] += t;
        __syncthreads();
    }
    if (i < n) row_off[i] = s[tid] - v;
    if (tid == 255) blk_sums[blockIdx.x] = s[255];
}

__global__ __launch_bounds__(256) void scan_sums(int* __restrict__ blk_sums, int nb) {
    __shared__ int s[256];
    int tid = threadIdx.x;
    int v = (tid < nb) ? blk_sums[tid] : 0;
    s[tid] = v;
    __syncthreads();
    #pragma unroll
    for (int off = 1; off < 256; off <<= 1) {
        int t = (tid >= off) ? s[tid - off] : 0;
        __syncthreads();
        s[tid] += t;
        __syncthreads();
    }
    if (tid < nb) blk_sums[tid] = s[tid] - v;
}

__global__ __launch_bounds__(256) void scan_add(int* __restrict__ row_off,
                                                const int* __restrict__ blk_sums,
                                                int n, int e) {
    int i = blockIdx.x * 256 + threadIdx.x;
    if (i < n) row_off[i] += blk_sums[blockIdx.x];
    if (i == 0) row_off[n] = e;
}

// atomic-free scatter: position = row_off[dst] + epos (ordinal captured in hist)
__global__ void scatter_kernel(const int* __restrict__ src, const int* __restrict__ dst,
                               const int* __restrict__ row_off, const int* __restrict__ epos,
                               const float* __restrict__ dinv,
                               int2* __restrict__ csr, int e) {
    int i = blockIdx.x * blockDim.x + threadIdx.x;
    int stride = gridDim.x * blockDim.x;
    for (; i < e; i += stride) {
        int s = src[i], d = dst[i];
        int pos = row_off[d] + epos[i];
        csr[pos] = make_int2(s, __float_as_int(dinv[s] * dinv[d]));
    }
}

// merged: x fp32->fp8 cast + W1/W2 transpose-cast (bf16) + zero deg/pool. One dispatch.
#define XCHUNKS (NN * FDIM / 4)            // 1,600,000 float4 groups
#define CAST_TOTAL (XCHUNKS + FDIM * HDIM + HDIM * HDIM + NN / 4 + GG * HDIM / 4)
__global__ __launch_bounds__(256) void cast_all(const float* __restrict__ x,
                                                unsigned char* __restrict__ x_f8,
                                                const float* __restrict__ W1,
                                                unsigned short* __restrict__ W1t,
                                                const float* __restrict__ W2,
                                                unsigned short* __restrict__ W2t,
                                                int* __restrict__ deg,
                                                float* __restrict__ pool) {
    int idx = blockIdx.x * 256 + threadIdx.x;
    if (idx < XCHUNKS) {
        int i = idx * 4;
        float4 v = *(const float4*)&x[i];
        *(unsigned*)&x_f8[i] = pack4_fp8(v.x, v.y, v.z, v.w);
        return;
    }
    int r = idx - XCHUNKS;
    if (r < FDIM * HDIM) {               // W1t[n][k] = bf16(W1[k][n]), K=128, Nc=256
        int nn = r / FDIM, k = r - nn * FDIM;
        W1t[r] = f2bf(W1[(size_t)k * HDIM + nn]);
        return;
    }
    r -= FDIM * HDIM;
    if (r < HDIM * HDIM) {               // W2t[n][k] = bf16(W2[k][n]), K=256, Nc=256
        int nn = r / HDIM, k = r - nn * HDIM;
        W2t[r] = f2bf(W2[(size_t)k * HDIM + nn]);
        return;
    }
    r -= HDIM * HDIM;
    if (r < NN / 4) {                    // zero deg (50000 % 4 == 0)
        int4 z = {0, 0, 0, 0};
        *(int4*)&deg[r * 4] = z;
        return;
    }
    r -= NN / 4;
    if (r < GG * HDIM / 4) {             // zero pool
        float4 z = {0.f, 0.f, 0.f, 0.f};
        *(float4*)&pool[r * 4] = z;
    }
}

// ---------------- GCN aggregation ----------------
// out[d] = sum_e in[src_e]*w_e + in[d]*dinv[d]^2 ; fp8 gather tables, fp32 accum, bf16 out.
// wave-per-node, dwordx4 (16B) gathers, wave split across edge slots.
// At the 8-XCD compulsory-traffic floor (FETCH = 8 x table bytes) -> fp8 halves the bytes.

__device__ __forceinline__ void fma16(const int4& g, float wgt, float* acc) {
    float f[16];
    dec4(g.x, f); dec4(g.y, f + 4); dec4(g.z, f + 8); dec4(g.w, f + 12);
    #pragma unroll
    for (int i = 0; i < 16; ++i) acc[i] = fmaf(f[i], wgt, acc[i]);
}

// L2 aggregation over fp8 h1 table: row = 256B; 16 lanes x 16B; 4 edge slots; 8 edges/iter.
__global__ __launch_bounds__(256) void gcn_agg256_fp8(const unsigned char* __restrict__ in,
                                                      const int* __restrict__ row_off,
                                                      const int2* __restrict__ csr,
                                                      const float* __restrict__ dinv,
                                                      unsigned short* __restrict__ out, int n) {
    int wave = threadIdx.x >> 6;
    int lane = threadIdx.x & 63;
    int node = blockIdx.x * 4 + wave;
    if (node >= n) return;
    int sub = lane >> 4;          // edge slot 0..3
    int fl  = lane & 15;          // 16B chunk within 256B row
    float di = dinv[node];
    float w0 = (sub == 0) ? di * di : 0.f;

    float acc[16];
    {   // self term
        int4 sv = *(const int4*)&in[(size_t)node * 256 + fl * 16];
        float f[16];
        dec4(sv.x, f); dec4(sv.y, f + 4); dec4(sv.z, f + 8); dec4(sv.w, f + 12);
        #pragma unroll
        for (int i = 0; i < 16; ++i) acc[i] = f[i] * w0;
    }

    int beg = __builtin_amdgcn_readfirstlane(row_off[node]);
    int end = __builtin_amdgcn_readfirstlane(row_off[node + 1]);
    int cnt = end - beg;
    if (cnt > 0) {
        int nIter = (cnt + 7) >> 3;                    // 8 edges / iter (2 gathers)
        int base = beg;
        int last = end - 1;
        int i0 = base + sub, i1 = base + 4 + sub;
        int2 c0 = csr[i0 < end ? i0 : last];
        int2 c1 = csr[i1 < end ? i1 : last];
        for (int it = 0; it < nIter; ++it) {
            int4 g0 = *(const int4*)&in[(size_t)c0.x * 256 + fl * 16];
            int4 g1 = *(const int4*)&in[(size_t)c1.x * 256 + fl * 16];
            float we0 = (base + sub < end) ? __int_as_float(c0.y) : 0.f;
            float we1 = (base + 4 + sub < end) ? __int_as_float(c1.y) : 0.f;
            int nb = base + 8;
            int j0 = nb + sub, j1 = nb + 4 + sub;
            int2 n0 = csr[j0 < end ? j0 : last];
            int2 n1 = csr[j1 < end ? j1 : last];
            fma16(g0, we0, acc); fma16(g1, we1, acc);
            c0 = n0; c1 = n1; base = nb;
        }
    }
    // combine 4 edge-slots (lanes sharing fl differ in bits 4..5)
    #pragma unroll
    for (int i = 0; i < 16; ++i) {
        acc[i] += __shfl_xor(acc[i], 16);
        acc[i] += __shfl_xor(acc[i], 32);
    }
    if (sub == 0) {
        int4 o0, o1;
        o0.x = (int)((unsigned)f2bf(acc[0])  | ((unsigned)f2bf(acc[1])  << 16));
        o0.y = (int)((unsigned)f2bf(acc[2])  | ((unsigned)f2bf(acc[3])  << 16));
        o0.z = (int)((unsigned)f2bf(acc[4])  | ((unsigned)f2bf(acc[5])  << 16));
        o0.w = (int)((unsigned)f2bf(acc[6])  | ((unsigned)f2bf(acc[7])  << 16));
        o1.x = (int)((unsigned)f2bf(acc[8])  | ((unsigned)f2bf(acc[9])  << 16));
        o1.y = (int)((unsigned)f2bf(acc[10]) | ((unsigned)f2bf(acc[11]) << 16));
        o1.z = (int)((unsigned)f2bf(acc[12]) | ((unsigned)f2bf(acc[13]) << 16));
        o1.w = (int)((unsigned)f2bf(acc[14]) | ((unsigned)f2bf(acc[15]) << 16));
        *(int4*)&out[(size_t)node * 256 + fl * 16] = o0;
        *(int4*)&out[(size_t)node * 256 + fl * 16 + 8] = o1;
    }
}

// R20: L1 aggregation over fp8 x table: row = 128 fp8 = 128B; 8 lanes x 16B per row;
// sub = lane>>3 -> 8 edge slots; 2 gathers -> 16 edges/iter. Output a0 bf16 [N][128].
__global__ __launch_bounds__(256) void gcn_agg128_fp8(const unsigned char* __restrict__ in,
                                                      const int* __restrict__ row_off,
                                                      const int2* __restrict__ csr,
                                                      const float* __restrict__ dinv,
                                                      unsigned short* __restrict__ out, int n) {
    int wave = threadIdx.x >> 6;
    int lane = threadIdx.x & 63;
    int node = blockIdx.x * 4 + wave;
    if (node >= n) return;
    int sub = lane >> 3;          // edge slot 0..7
    int fl  = lane & 7;           // 16B chunk within 128B row
    float di = dinv[node];
    float w0 = (sub == 0) ? di * di : 0.f;

    float acc[16];
    {   // self term
        int4 sv = *(const int4*)&in[(size_t)node * 128 + fl * 16];
        float f[16];
        dec4(sv.x, f); dec4(sv.y, f + 4); dec4(sv.z, f + 8); dec4(sv.w, f + 12);
        #pragma unroll
        for (int i = 0; i < 16; ++i) acc[i] = f[i] * w0;
    }

    int beg = __builtin_amdgcn_readfirstlane(row_off[node]);
    int end = __builtin_amdgcn_readfirstlane(row_off[node + 1]);
    int cnt = end - beg;
    if (cnt > 0) {
        int nIter = (cnt + 15) >> 4;                   // 16 edges / iter (2 gathers)
        int base = beg;
        int last = end - 1;
        int i0 = base + sub, i1 = base + 8 + sub;
        int2 c0 = csr[i0 < end ? i0 : last];
        int2 c1 = csr[i1 < end ? i1 : last];
        for (int it = 0; it < nIter; ++it) {
            int4 g0 = *(const int4*)&in[(size_t)c0.x * 128 + fl * 16];
            int4 g1 = *(const int4*)&in[(size_t)c1.x * 128 + fl * 16];
            float we0 = (base + sub < end) ? __int_as_float(c0.y) : 0.f;
            float we1 = (base + 8 + sub < end) ? __int_as_float(c1.y) : 0.f;
            int nb = base + 16;
            int j0 = nb + sub, j1 = nb + 8 + sub;
            int2 n0 = csr[j0 < end ? j0 : last];
            int2 n1 = csr[j1 < end ? j1 : last];
            fma16(g0, we0, acc); fma16(g1, we1, acc);
            c0 = n0; c1 = n1; base = nb;
        }
    }
    // combine 8 edge-slots (lanes sharing fl differ in bits 3..5)
    #pragma unroll
    for (int i = 0; i < 16; ++i) {
        acc[i] += __shfl_xor(acc[i], 8);
        acc[i] += __shfl_xor(acc[i], 16);
        acc[i] += __shfl_xor(acc[i], 32);
    }
    if (sub == 0) {
        int4 o0, o1;
        o0.x = (int)((unsigned)f2bf(acc[0])  | ((unsigned)f2bf(acc[1])  << 16));
        o0.y = (int)((unsigned)f2bf(acc[2])  | ((unsigned)f2bf(acc[3])  << 16));
        o0.z = (int)((unsigned)f2bf(acc[4])  | ((unsigned)f2bf(acc[5])  << 16));
        o0.w = (int)((unsigned)f2bf(acc[6])  | ((unsigned)f2bf(acc[7])  << 16));
        o1.x = (int)((unsigned)f2bf(acc[8])  | ((unsigned)f2bf(acc[9])  << 16));
        o1.y = (int)((unsigned)f2bf(acc[10]) | ((unsigned)f2bf(acc[11]) << 16));
        o1.z = (int)((unsigned)f2bf(acc[12]) | ((unsigned)f2bf(acc[13]) << 16));
        o1.w = (int)((unsigned)f2bf(acc[14]) | ((unsigned)f2bf(acc[15]) << 16));
        *(int4*)&out[(size_t)node * 128 + fl * 16] = o0;
        *(int4*)&out[(size_t)node * 128 + fl * 16 + 8] = o1;
    }
}

// ---------------- bf16 MFMA GEMM, 128x128 tiles, dbuf, 8 waves (2x4 of 64x32) ----------------
// grid (ceil(M/128), 2): bn = blockIdx.y*128. Per K-step each thread stages one 16B
// A-chunk + one 16B B-chunk via global_load_lds into LINEAR LDS (LDT=32). Double-buffered:
// STAGE(next) issued BEFORE compute(cur); single __syncthreads per step (drains vmcnt).
// Wave tile 64x32: acc[4][2]. Verified frag layouts (learn_hip m89/m91/m120).

__global__ __launch_bounds__(512, 2) void gemm1_mfma_bias_relu(
        const unsigned short* __restrict__ A,    // [M][128] bf16
        const unsigned short* __restrict__ Bt,   // [256][128] bf16
        const float* __restrict__ bias,          // [256] fp32
        unsigned char* __restrict__ C, int M) {  // [M][256] fp8 e4m3
    constexpr int K = FDIM, Nc = HDIM, LDT = 32;
    __shared__ unsigned short As[2][128 * LDT];  // 8KB per buffer
    __shared__ unsigned short Bs[2][128 * LDT];
    int tid = threadIdx.x;
    int lane = tid & 63, wave = tid >> 6;
    int wm = (wave >> 2) * 64;                   // 0 | 64
    int wn2 = (wave & 3) * 32;                   // 0,32,64,96
    int bm = blockIdx.x * 128;
    int bn = blockIdx.y * 128;
    int l15 = lane & 15, quad = lane >> 4;
    int srow = tid >> 2, sq = (tid & 3) * 8;     // staging: row 0..127, k-subchunk

    floatx4 zero = {0.f, 0.f, 0.f, 0.f};
    floatx4 acc[4][2];
    #pragma unroll
    for (int s = 0; s < 4; ++s)
        #pragma unroll
        for (int t = 0; t < 2; ++t) acc[s][t] = zero;

    // prologue: stage k0=0 into buf 0
    gload16(&A[(size_t)(bm + srow) * K + sq], &As[0][wave * 512]);
    gload16(&Bt[(size_t)(bn + srow) * K + sq], &Bs[0][wave * 512]);
    __syncthreads();
    int cur = 0;
    for (int k0 = 0; k0 < K; k0 += 32) {
        if (k0 + 32 < K) {   // stage next K-step into the other buffer
            gload16(&A[(size_t)(bm + srow) * K + k0 + 32 + sq], &As[cur ^ 1][wave * 512]);
            gload16(&Bt[(size_t)(bn + srow) * K + k0 + 32 + sq], &Bs[cur ^ 1][wave * 512]);
        }
        short8 af[4], bf[2];
        #pragma unroll
        for (int s = 0; s < 4; ++s)
            af[s] = *(const short8*)&As[cur][(wm + s * 16 + l15) * LDT + quad * 8];
        #pragma unroll
        for (int t = 0; t < 2; ++t)
            bf[t] = *(const short8*)&Bs[cur][(wn2 + t * 16 + l15) * LDT + quad * 8];
        #pragma unroll
        for (int s = 0; s < 4; ++s)
            #pragma unroll
            for (int t = 0; t < 2; ++t)
                acc[s][t] = __builtin_amdgcn_mfma_f32_16x16x32_bf16(af[s], bf[t], acc[s][t], 0, 0, 0);
        __syncthreads();                          // drains stage vmcnt + LDS reads
        cur ^= 1;
    }
    #pragma unroll
    for (int s = 0; s < 4; ++s) {
        int row0 = bm + wm + s * 16 + quad * 4;
        #pragma unroll
        for (int t = 0; t < 2; ++t) {
            int col = bn + wn2 + t * 16 + l15;
            float bb = bias[col];
            #pragma unroll
            for (int r = 0; r < 4; ++r) {
                int row = row0 + r;
                if (row < M)
                    C[(size_t)row * Nc + col] = enc8(fmaxf(acc[s][t][r] + bb, 0.f));
            }
        }
    }
}

// GEMM2 fused with mean-pool numerator. R19 epilogue: per-graph LDS reduction
// (part[ngr][128] via LDS atomics, reusing staging LDS), then ngr*128 global atomics
// per block instead of 4096. Fallback to direct atomics if ngr > 8.
__global__ __launch_bounds__(512, 2) void gemm2_pool(
        const unsigned short* __restrict__ A,    // [M][256] bf16 (a1b)
        const unsigned short* __restrict__ Bt,   // [256][256] bf16
        const float* __restrict__ bias,          // [256] fp32
        const int* __restrict__ batch,           // [M] sorted graph ids
        float* __restrict__ pool, int M) {       // [G][256] fp32, pre-zeroed
    constexpr int K = HDIM, Nc = HDIM, LDT = 32;
    constexpr int NGR_CAP = 8;
    __shared__ unsigned short As[2][128 * LDT];
    __shared__ unsigned short Bs[2][128 * LDT];
    int tid = threadIdx.x;
    int lane = tid & 63, wave = tid >> 6;
    int wm = (wave >> 2) * 64;
    int wn2 = (wave & 3) * 32;
    int bm = blockIdx.x * 128;
    int bn = blockIdx.y * 128;
    int l15 = lane & 15, quad = lane >> 4;
    int srow = tid >> 2, sq = (tid & 3) * 8;

    floatx4 zero = {0.f, 0.f, 0.f, 0.f};
    floatx4 acc[4][2];
    #pragma unroll
    for (int s = 0; s < 4; ++s)
        #pragma unroll
        for (int t = 0; t < 2; ++t) acc[s][t] = zero;

    gload16(&A[(size_t)(bm + srow) * K + sq], &As[0][wave * 512]);
    gload16(&Bt[(size_t)(bn + srow) * K + sq], &Bs[0][wave * 512]);
    __syncthreads();
    int cur = 0;
    for (int k0 = 0; k0 < K; k0 += 32) {
        if (k0 + 32 < K) {
            gload16(&A[(size_t)(bm + srow) * K + k0 + 32 + sq], &As[cur ^ 1][wave * 512]);
            gload16(&Bt[(size_t)(bn + srow) * K + k0 + 32 + sq], &Bs[cur ^ 1][wave * 512]);
        }
        short8 af[4], bf[2];
        #pragma unroll
        for (int s = 0; s < 4; ++s)
            af[s] = *(const short8*)&As[cur][(wm + s * 16 + l15) * LDT + quad * 8];
        #pragma unroll
        for (int t = 0; t < 2; ++t)
            bf[t] = *(const short8*)&Bs[cur][(wn2 + t * 16 + l15) * LDT + quad * 8];
        #pragma unroll
        for (int s = 0; s < 4; ++s)
            #pragma unroll
            for (int t = 0; t < 2; ++t)
                acc[s][t] = __builtin_amdgcn_mfma_f32_16x16x32_bf16(af[s], bf[t], acc[s][t], 0, 0, 0);
        __syncthreads();
        cur ^= 1;
    }
    // ---- R19 epilogue ----
    float* part = (float*)&As[0][0];            // NGR_CAP*128 floats = 4KB
    int lastRow = min(bm + 127, M - 1);
    int gfirst = batch[bm];
    int glast = batch[lastRow];
    int ngr = glast - gfirst + 1;
    if (ngr <= NGR_CAP) {
        for (int i = tid; i < ngr * 128; i += 512) part[i] = 0.f;
        __syncthreads();
        #pragma unroll
        for (int s = 0; s < 4; ++s) {
            int row0 = bm + wm + s * 16 + quad * 4;
            if (row0 >= M) continue;
            int gA = batch[row0];
            bool full = (row0 + 3 < M);
            bool same = full && (batch[row0 + 3] == gA);
            #pragma unroll
            for (int t = 0; t < 2; ++t) {
                int colL = wn2 + t * 16 + l15;
                float bb = bias[bn + colL];
                if (same) {
                    float v = fmaxf(acc[s][t][0] + bb, 0.f) + fmaxf(acc[s][t][1] + bb, 0.f)
                            + fmaxf(acc[s][t][2] + bb, 0.f) + fmaxf(acc[s][t][3] + bb, 0.f);
                    atomicAdd(&part[(gA - gfirst) * 128 + colL], v);
                } else {
                    #pragma unroll
                    for (int r = 0; r < 4; ++r) {
                        int row = row0 + r;
                        if (row < M) {
                            float v = fmaxf(acc[s][t][r] + bb, 0.f);
                            atomicAdd(&part[(batch[row] - gfirst) * 128 + colL], v);
                        }
                    }
                }
            }
        }
        __syncthreads();
        for (int i = tid; i < ngr * 128; i += 512) {
            float v = part[i];
            if (v != 0.f)
                atomicAdd(&pool[(size_t)(gfirst + (i >> 7)) * Nc + bn + (i & 127)], v);
        }
    } else {
        #pragma unroll
        for (int s = 0; s < 4; ++s) {
            int row0 = bm + wm + s * 16 + quad * 4;
            if (row0 >= M) continue;
            #pragma unroll
            for (int t = 0; t < 2; ++t) {
                int col = bn + wn2 + t * 16 + l15;
                float bb = bias[col];
                #pragma unroll
                for (int r = 0; r < 4; ++r) {
                    int row = row0 + r;
                    if (row < M) {
                        float v = fmaxf(acc[s][t][r] + bb, 0.f);
                        atomicAdd(&pool[(size_t)batch[row] * Nc + col], v);
                    }
                }
            }
        }
    }
}

// ---------------- head: one block per graph, reads pooled sums ----------------

__device__ __forceinline__ int lower_bound_i(const int* __restrict__ a, int n, int v) {
    int lo = 0, hi = n;
    while (lo < hi) {
        int mid = (lo + hi) >> 1;
        if (a[mid] < v) lo = mid + 1; else hi = mid;
    }
    return lo;
}

__global__ __launch_bounds__(256) void head_kernel(const float* __restrict__ pool,
                                                   const int* __restrict__ batch,
                                                   const float* __restrict__ num_atoms,
                                                   const float* __restrict__ W3, const float* __restrict__ b3,
                                                   const float* __restrict__ W4, const float* __restrict__ b4,
                                                   float* __restrict__ out, int n) {
    int g = blockIdx.x;
    int tid = threadIdx.x;
    __shared__ int s_lo, s_hi;
    if (tid == 0) {
        s_lo = lower_bound_i(batch, n, g);
        s_hi = lower_bound_i(batch, n, g + 1);
    }
    __syncthreads();
    float cnt = (float)(s_hi - s_lo);

    __shared__ float zin[HDIM + 1];
    __shared__ float z[32];
    zin[tid] = pool[(size_t)g * HDIM + tid] / fmaxf(cnt, 1.0f);
    if (tid == 0) zin[HDIM] = num_atoms[g];
    __syncthreads();
    if (tid < 32) {
        float a = b3[tid];
        for (int k = 0; k < HDIM + 1; ++k) a = fmaf(zin[k], W3[k * 32 + tid], a);
        z[tid] = fmaxf(a, 0.f);
    }
    __syncthreads();
    if (tid < 4) {
        float a = b4[tid];
        #pragma unroll
        for (int k = 0; k < 32; ++k) a = fmaf(z[k], W4[k * 4 + tid], a);
        out[g * 4 + tid] = a;
    }
}

// ---------------- launch ----------------

extern "C" void kernel_launch(void* const* d_in, const int* in_sizes, int n_in,
                              void* d_out, int out_size, void* d_ws, size_t ws_size,
                              hipStream_t stream) {
    const float* x         = (const float*)d_in[0];
    const int*   edge_idx  = (const int*)d_in[1];
    const int*   batch     = (const int*)d_in[2];
    const float* num_atoms = (const float*)d_in[3];
    const float* W1 = (const float*)d_in[4];
    const float* b1 = (const float*)d_in[5];
    const float* W2 = (const float*)d_in[6];
    const float* b2 = (const float*)d_in[7];
    const float* W3 = (const float*)d_in[8];
    const float* b3 = (const float*)d_in[9];
    const float* W4 = (const float*)d_in[10];
    const float* b4 = (const float*)d_in[11];
    float* out = (float*)d_out;

    const int n = NN, e = EE;
    const int* e_src = edge_idx;
    const int* e_dst = edge_idx + e;

    // workspace (256B aligned). Lifetime aliasing:
    //   x_f8 (6.4MB): [N,128] fp8 (cast_all out, dead after agg128).
    //   P (25.6MB): a0b [N,128]bf16 (first half, dead after gemm1); whole P reused as
    //               a1b [N,256]bf16 (agg256 out). Absorbs gemm1 A-staging over-reads.
    //   Q (12.8MB): h1f8 [N,256]fp8 (gemm1 out, dead after agg256). Absorbs gemm2
    //               A-staging over-reads past row M.
    //   pool (512KB): [G,256] fp32 pooled sums (gemm2_pool out -> head).
    char* ws = (char*)d_ws;
    size_t off = 0;
    auto carve = [&](size_t bytes) -> void* {
        void* p = ws + off;
        off = (off + bytes + 255) & ~(size_t)255;
        return p;
    };
    int*   deg_i    = (int*)carve((size_t)n * 4);
    int*   row_off  = (int*)carve((size_t)(n + 1) * 4);
    int*   blk_sums = (int*)carve((size_t)256 * 4);
    float* dinv     = (float*)carve((size_t)n * 4);
    int*   epos     = (int*)carve((size_t)e * 4);
    unsigned short* W1t = (unsigned short*)carve((size_t)FDIM * HDIM * 2);
    unsigned short* W2t = (unsigned short*)carve((size_t)HDIM * HDIM * 2);
    int2*  csr      = (int2*)carve((size_t)e * 8);
    unsigned char* x_f8 = (unsigned char*)carve((size_t)n * FDIM);
    unsigned short* P = (unsigned short*)carve((size_t)n * HDIM * 2);
    unsigned char*  Q = (unsigned char*)carve((size_t)n * HDIM);
    float* pool     = (float*)carve((size_t)GG * HDIM * 4);
    unsigned short* a0b  = P;                       // [N,128] bf16
    unsigned short* a1b  = P;                       // [N,256] bf16 (a0b dead)
    unsigned char*  h1f8 = Q;                       // [N,256] fp8 e4m3
    (void)ws_size; (void)n_in; (void)in_sizes; (void)out_size;

    // cast x (fp8) + transpose-cast W1,W2 + zero deg/pool, one dispatch (must precede hist)
    cast_all<<<(CAST_TOTAL + 255) / 256, 256, 0, stream>>>(
        x, x_f8, W1, W1t, W2, W2t, deg_i, pool);
    hist_kernel<<<1024, 256, 0, stream>>>(e_dst, deg_i, epos, e);
    scan_part<<<SCAN_NB, 256, 0, stream>>>(deg_i, row_off, blk_sums, dinv, n);
    scan_sums<<<1, 256, 0, stream>>>(blk_sums, SCAN_NB);
    scan_add<<<SCAN_NB, 256, 0, stream>>>(row_off, blk_sums, n, e);
    scatter_kernel<<<1024, 256, 0, stream>>>(e_src, e_dst, row_off, epos, dinv, csr, e);

    dim3 gemm_grid((n + 127) / 128, 2);
    // L1: a0 = agg(x_f8) bf16; h1f8 = fp8(relu(a0 @ W1 + b1))
    gcn_agg128_fp8<<<(n + 3) / 4, 256, 0, stream>>>(x_f8, row_off, csr, dinv, a0b, n);
    gemm1_mfma_bias_relu<<<gemm_grid, 512, 0, stream>>>(a0b, W1t, b1, h1f8, n);
    // L2: a1 = agg(h1f8) bf16; pool += segsum(relu(a1 @ W2 + b2))
    gcn_agg256_fp8<<<(n + 3) / 4, 256, 0, stream>>>(h1f8, row_off, csr, dinv, a1b, n);
    gemm2_pool<<<gemm_grid, 512, 0, stream>>>(a1b, W2t, b2, batch, pool, n);
    // head
    head_kernel<<<GG, 256, 0, stream>>>(pool, batch, num_atoms, W3, b3, W4, b4, out, n);
}

// Round 14
// 285.766 us; speedup vs baseline: 1.0509x; 1.0028x over previous
//
#include <hip/hip_runtime.h>
#include <hip/hip_bf16.h>
#include <hip/hip_fp8.h>

// GNN: 2-layer GCN (N=50000, E=800000, F=128, H=256) + mean-pool (G=512) + MLP head (257->32->4)
// Key identity: segment_sum((xW)[src]*norm) == (segment_sum(x[src]*norm)) @ W  (GCN agg is linear)
//   prep:  memset(deg) -> cast_hist (x->FP8, W transpose, zero pool, hist+epos) ->
//          scan_part -> scan_sums -> scatter (prefix applied inline; scan_add eliminated)
//   L1: agg128_fp8(x_f8) -> a0 bf16; h1 = relu(a0 @ W1 + b1) -> FP8 e4m3  [MFMA dbuf tiles]
//   L2: agg256_fp8(h1) -> a1 bf16; gemm2_pool: relu(a1 @ W2 + b2) pooled into pool[G,256]
//   head: per-graph block: mean + 257->32->4 MLP
// R8/R9: agg at 8-XCD compulsory BYTES floor. R11/R13: sliced agg abandoned. R15: agg+GEMM
//   fusion refuted (TLP loss). R16: atomic-free scatter. R17/R20: fp8 gather tables
//   (halved agg bytes; absmax UNCHANGED). R18: gemm2 invariant under occupancy/dbuf =>
//   atomic-bound. R19: per-graph LDS reduction epilogue (3.2M -> 250K atomics; ->287).
// R21: serialization cuts: (a) deg zero via memset, hist merged INTO cast kernel (atomic
//   latency hides under streaming cast); (b) scan_add eliminated - consumers apply
//   off(i) = row_off[i] + blk_sums[i>>8] inline. 11 -> 10 dispatches.

#define NN 50000
#define EE 800000
#define FDIM 128
#define HDIM 256
#define GG 512
#define SCAN_NB ((NN + 255) / 256)
#define HIST_T 262144            // hist thread count inside cast_hist

typedef __attribute__((ext_vector_type(8))) short short8;     // 8 bf16 = 4 VGPRs (MFMA A/B frag)
typedef __attribute__((ext_vector_type(4))) float floatx4;    // MFMA C/D frag
typedef __attribute__((ext_vector_type(2))) float floatx2;

__device__ __forceinline__ unsigned short f2bf(float f) {   // RNE
    unsigned u = __float_as_uint(f);
    return (unsigned short)((u + 0x7FFF + ((u >> 16) & 1)) >> 16);
}
__device__ __forceinline__ float bflo(unsigned v) { return __uint_as_float(v << 16); }
__device__ __forceinline__ float bfhi(unsigned v) { return __uint_as_float(v & 0xFFFF0000u); }

// fp8 e4m3 (OCP on gfx950) encode/decode via HW cvt; fallback to hip_fp8 type.
__device__ __forceinline__ unsigned char enc8(float v) {
#if defined(__has_builtin) && __has_builtin(__builtin_amdgcn_cvt_pk_fp8_f32)
    return (unsigned char)(__builtin_amdgcn_cvt_pk_fp8_f32(v, v, 0, false) & 0xFF);
#else
    __hip_fp8_e4m3 q(v);
    return (unsigned char)q.__x;
#endif
}
__device__ __forceinline__ unsigned pack4_fp8(float a, float b, float c, float d) {
#if defined(__has_builtin) && __has_builtin(__builtin_amdgcn_cvt_pk_fp8_f32)
    unsigned lo = (unsigned)__builtin_amdgcn_cvt_pk_fp8_f32(a, b, 0, false) & 0xFFFFu;
    unsigned hi = (unsigned)__builtin_amdgcn_cvt_pk_fp8_f32(c, d, 0, false) & 0xFFFFu;
    return lo | (hi << 16);
#else
    return (unsigned)enc8(a) | ((unsigned)enc8(b) << 8) |
           ((unsigned)enc8(c) << 16) | ((unsigned)enc8(d) << 24);
#endif
}
__device__ __forceinline__ void dec4(int d, float* f) {   // 4 fp8 bytes -> 4 floats
#if defined(__has_builtin) && __has_builtin(__builtin_amdgcn_cvt_pk_f32_fp8)
    floatx2 lo = __builtin_amdgcn_cvt_pk_f32_fp8(d, false);
    floatx2 hi = __builtin_amdgcn_cvt_pk_f32_fp8(d, true);
    f[0] = lo.x; f[1] = lo.y; f[2] = hi.x; f[3] = hi.y;
#else
    unsigned u = (unsigned)d;
    #pragma unroll
    for (int i = 0; i < 4; ++i) {
        __hip_fp8_e4m3 t; t.__x = (__hip_fp8_storage_t)((u >> (8 * i)) & 0xFF);
        f[i] = (float)t;
    }
#endif
}

// async global->LDS, 16B per lane. lds ptr must be wave-uniform (HW adds lane*16).
__device__ __forceinline__ void gload16(const void* g, void* l) {
    __builtin_amdgcn_global_load_lds((const __attribute__((address_space(1))) void*)g,
                                     (__attribute__((address_space(3))) void*)l, 16, 0, 0);
}

// ---------------- prep kernels ----------------

// merged: x fp32->fp8 cast + W1/W2 transpose-cast (bf16) + zero pool + HIST (deg pre-zeroed
// by memset). All ranges independent -> hist atomic latency hides under streaming cast.
#define XCHUNKS (NN * FDIM / 4)            // 1,600,000 float4 groups
#define CAST_TOTAL (XCHUNKS + FDIM * HDIM + HDIM * HDIM + GG * HDIM / 4 + HIST_T)
__global__ __launch_bounds__(256) void cast_hist(const float* __restrict__ x,
                                                 unsigned char* __restrict__ x_f8,
                                                 const float* __restrict__ W1,
                                                 unsigned short* __restrict__ W1t,
                                                 const float* __restrict__ W2,
                                                 unsigned short* __restrict__ W2t,
                                                 float* __restrict__ pool,
                                                 const int* __restrict__ dst,
                                                 int* __restrict__ deg,
                                                 int* __restrict__ epos, int e) {
    int idx = blockIdx.x * 256 + threadIdx.x;
    if (idx < XCHUNKS) {
        int i = idx * 4;
        float4 v = *(const float4*)&x[i];
        *(unsigned*)&x_f8[i] = pack4_fp8(v.x, v.y, v.z, v.w);
        return;
    }
    int r = idx - XCHUNKS;
    if (r < FDIM * HDIM) {               // W1t[n][k] = bf16(W1[k][n]), K=128, Nc=256
        int nn = r / FDIM, k = r - nn * FDIM;
        W1t[r] = f2bf(W1[(size_t)k * HDIM + nn]);
        return;
    }
    r -= FDIM * HDIM;
    if (r < HDIM * HDIM) {               // W2t[n][k] = bf16(W2[k][n]), K=256, Nc=256
        int nn = r / HDIM, k = r - nn * HDIM;
        W2t[r] = f2bf(W2[(size_t)k * HDIM + nn]);
        return;
    }
    r -= HDIM * HDIM;
    if (r < GG * HDIM / 4) {             // zero pool
        float4 z = {0.f, 0.f, 0.f, 0.f};
        *(float4*)&pool[r * 4] = z;
        return;
    }
    r -= GG * HDIM / 4;
    if (r < HIST_T) {                    // hist + per-edge ordinal
        for (int i = r; i < e; i += HIST_T) epos[i] = atomicAdd(&deg[dst[i]], 1);
    }
}

__global__ __launch_bounds__(256) void scan_part(const int* __restrict__ deg,
                                                 int* __restrict__ row_off,
                                                 int* __restrict__ blk_sums,
                                                 float* __restrict__ dinv, int n) {
    __shared__ int s[256];
    int tid = threadIdx.x;
    int i = blockIdx.x * 256 + tid;
    int v = (i < n) ? deg[i] : 0;
    if (i < n) dinv[i] = rsqrtf((float)v + 1.0f);
    s[tid] = v;
    __syncthreads();
    #pragma unroll
    for (int off = 1; off < 256; off <<= 1) {
        int t = (tid >= off) ? s[tid - off] : 0;
        __syncthreads();
        s[tid] += t;
        __syncthreads();
    }
    if (i < n) row_off[i] = s[tid] - v;
    if (tid == 255) blk_sums[blockIdx.x] = s[255];
}

__global__ __launch_bounds__(256) void scan_sums(int* __restrict__ blk_sums, int nb) {
    __shared__ int s[256];
    int tid = threadIdx.x;
    int v = (tid < nb) ? blk_sums[tid] : 0;
    s[tid] = v;
    __syncthreads();
    #pragma unroll
    for (int off = 1; off < 256; off <<= 1) {
        int t = (tid >= off) ? s[tid - off] : 0;
        __syncthreads();
        s[tid] += t;
        __syncthreads();
    }
    if (tid < nb) blk_sums[tid] = s[tid] - v;
}

// atomic-free scatter; final offset = row_off[d] + blk_sums[d>>8] + epos[i]
__global__ void scatter_kernel(const int* __restrict__ src, const int* __restrict__ dst,
                               const int* __restrict__ row_off, const int* __restrict__ blk_sums,
                               const int* __restrict__ epos,
                               const float* __restrict__ dinv,
                               int2* __restrict__ csr, int e) {
    int i = blockIdx.x * blockDim.x + threadIdx.x;
    int stride = gridDim.x * blockDim.x;
    for (; i < e; i += stride) {
        int s = src[i], d = dst[i];
        int pos = row_off[d] + blk_sums[d >> 8] + epos[i];
        csr[pos] = make_int2(s, __float_as_int(dinv[s] * dinv[d]));
    }
}

// ---------------- GCN aggregation ----------------
// out[d] = sum_e in[src_e]*w_e + in[d]*dinv[d]^2 ; fp8 gather tables, fp32 accum, bf16 out.
// wave-per-node, dwordx4 (16B) gathers, wave split across edge slots.
// Row ranges computed inline: off(i) = row_off[i] + blk_sums[i>>8]; off(n) = EE.

__device__ __forceinline__ void fma16(const int4& g, float wgt, float* acc) {
    float f[16];
    dec4(g.x, f); dec4(g.y, f + 4); dec4(g.z, f + 8); dec4(g.w, f + 12);
    #pragma unroll
    for (int i = 0; i < 16; ++i) acc[i] = fmaf(f[i], wgt, acc[i]);
}

__device__ __forceinline__ int row_begin(const int* ro, const int* bs, int i) {
    return ro[i] + bs[i >> 8];
}

// L2 aggregation over fp8 h1 table: row = 256B; 16 lanes x 16B; 4 edge slots; 8 edges/iter.
__global__ __launch_bounds__(256) void gcn_agg256_fp8(const unsigned char* __restrict__ in,
                                                      const int* __restrict__ row_off,
                                                      const int* __restrict__ blk_sums,
                                                      const int2* __restrict__ csr,
                                                      const float* __restrict__ dinv,
                                                      unsigned short* __restrict__ out, int n) {
    int wave = threadIdx.x >> 6;
    int lane = threadIdx.x & 63;
    int node = blockIdx.x * 4 + wave;
    if (node >= n) return;
    int sub = lane >> 4;          // edge slot 0..3
    int fl  = lane & 15;          // 16B chunk within 256B row
    float di = dinv[node];
    float w0 = (sub == 0) ? di * di : 0.f;

    float acc[16];
    {   // self term
        int4 sv = *(const int4*)&in[(size_t)node * 256 + fl * 16];
        float f[16];
        dec4(sv.x, f); dec4(sv.y, f + 4); dec4(sv.z, f + 8); dec4(sv.w, f + 12);
        #pragma unroll
        for (int i = 0; i < 16; ++i) acc[i] = f[i] * w0;
    }

    int beg = __builtin_amdgcn_readfirstlane(row_begin(row_off, blk_sums, node));
    int end = __builtin_amdgcn_readfirstlane(
        (node + 1 < n) ? row_begin(row_off, blk_sums, node + 1) : EE);
    int cnt = end - beg;
    if (cnt > 0) {
        int nIter = (cnt + 7) >> 3;                    // 8 edges / iter (2 gathers)
        int base = beg;
        int last = end - 1;
        int i0 = base + sub, i1 = base + 4 + sub;
        int2 c0 = csr[i0 < end ? i0 : last];
        int2 c1 = csr[i1 < end ? i1 : last];
        for (int it = 0; it < nIter; ++it) {
            int4 g0 = *(const int4*)&in[(size_t)c0.x * 256 + fl * 16];
            int4 g1 = *(const int4*)&in[(size_t)c1.x * 256 + fl * 16];
            float we0 = (base + sub < end) ? __int_as_float(c0.y) : 0.f;
            float we1 = (base + 4 + sub < end) ? __int_as_float(c1.y) : 0.f;
            int nb = base + 8;
            int j0 = nb + sub, j1 = nb + 4 + sub;
            int2 n0 = csr[j0 < end ? j0 : last];
            int2 n1 = csr[j1 < end ? j1 : last];
            fma16(g0, we0, acc); fma16(g1, we1, acc);
            c0 = n0; c1 = n1; base = nb;
        }
    }
    // combine 4 edge-slots (lanes sharing fl differ in bits 4..5)
    #pragma unroll
    for (int i = 0; i < 16; ++i) {
        acc[i] += __shfl_xor(acc[i], 16);
        acc[i] += __shfl_xor(acc[i], 32);
    }
    if (sub == 0) {
        int4 o0, o1;
        o0.x = (int)((unsigned)f2bf(acc[0])  | ((unsigned)f2bf(acc[1])  << 16));
        o0.y = (int)((unsigned)f2bf(acc[2])  | ((unsigned)f2bf(acc[3])  << 16));
        o0.z = (int)((unsigned)f2bf(acc[4])  | ((unsigned)f2bf(acc[5])  << 16));
        o0.w = (int)((unsigned)f2bf(acc[6])  | ((unsigned)f2bf(acc[7])  << 16));
        o1.x = (int)((unsigned)f2bf(acc[8])  | ((unsigned)f2bf(acc[9])  << 16));
        o1.y = (int)((unsigned)f2bf(acc[10]) | ((unsigned)f2bf(acc[11]) << 16));
        o1.z = (int)((unsigned)f2bf(acc[12]) | ((unsigned)f2bf(acc[13]) << 16));
        o1.w = (int)((unsigned)f2bf(acc[14]) | ((unsigned)f2bf(acc[15]) << 16));
        *(int4*)&out[(size_t)node * 256 + fl * 16] = o0;
        *(int4*)&out[(size_t)node * 256 + fl * 16 + 8] = o1;
    }
}

// L1 aggregation over fp8 x table: row = 128B; 8 lanes x 16B; 8 edge slots; 16 edges/iter.
__global__ __launch_bounds__(256) void gcn_agg128_fp8(const unsigned char* __restrict__ in,
                                                      const int* __restrict__ row_off,
                                                      const int* __restrict__ blk_sums,
                                                      const int2* __restrict__ csr,
                                                      const float* __restrict__ dinv,
                                                      unsigned short* __restrict__ out, int n) {
    int wave = threadIdx.x >> 6;
    int lane = threadIdx.x & 63;
    int node = blockIdx.x * 4 + wave;
    if (node >= n) return;
    int sub = lane >> 3;          // edge slot 0..7
    int fl  = lane & 7;           // 16B chunk within 128B row
    float di = dinv[node];
    float w0 = (sub == 0) ? di * di : 0.f;

    float acc[16];
    {   // self term
        int4 sv = *(const int4*)&in[(size_t)node * 128 + fl * 16];
        float f[16];
        dec4(sv.x, f); dec4(sv.y, f + 4); dec4(sv.z, f + 8); dec4(sv.w, f + 12);
        #pragma unroll
        for (int i = 0; i < 16; ++i) acc[i] = f[i] * w0;
    }

    int beg = __builtin_amdgcn_readfirstlane(row_begin(row_off, blk_sums, node));
    int end = __builtin_amdgcn_readfirstlane(
        (node + 1 < n) ? row_begin(row_off, blk_sums, node + 1) : EE);
    int cnt = end - beg;
    if (cnt > 0) {
        int nIter = (cnt + 15) >> 4;                   // 16 edges / iter (2 gathers)
        int base = beg;
        int last = end - 1;
        int i0 = base + sub, i1 = base + 8 + sub;
        int2 c0 = csr[i0 < end ? i0 : last];
        int2 c1 = csr[i1 < end ? i1 : last];
        for (int it = 0; it < nIter; ++it) {
            int4 g0 = *(const int4*)&in[(size_t)c0.x * 128 + fl * 16];
            int4 g1 = *(const int4*)&in[(size_t)c1.x * 128 + fl * 16];
            float we0 = (base + sub < end) ? __int_as_float(c0.y) : 0.f;
            float we1 = (base + 8 + sub < end) ? __int_as_float(c1.y) : 0.f;
            int nb = base + 16;
            int j0 = nb + sub, j1 = nb + 8 + sub;
            int2 n0 = csr[j0 < end ? j0 : last];
            int2 n1 = csr[j1 < end ? j1 : last];
            fma16(g0, we0, acc); fma16(g1, we1, acc);
            c0 = n0; c1 = n1; base = nb;
        }
    }
    // combine 8 edge-slots (lanes sharing fl differ in bits 3..5)
    #pragma unroll
    for (int i = 0; i < 16; ++i) {
        acc[i] += __shfl_xor(acc[i], 8);
        acc[i] += __shfl_xor(acc[i], 16);
        acc[i] += __shfl_xor(acc[i], 32);
    }
    if (sub == 0) {
        int4 o0, o1;
        o0.x = (int)((unsigned)f2bf(acc[0])  | ((unsigned)f2bf(acc[1])  << 16));
        o0.y = (int)((unsigned)f2bf(acc[2])  | ((unsigned)f2bf(acc[3])  << 16));
        o0.z = (int)((unsigned)f2bf(acc[4])  | ((unsigned)f2bf(acc[5])  << 16));
        o0.w = (int)((unsigned)f2bf(acc[6])  | ((unsigned)f2bf(acc[7])  << 16));
        o1.x = (int)((unsigned)f2bf(acc[8])  | ((unsigned)f2bf(acc[9])  << 16));
        o1.y = (int)((unsigned)f2bf(acc[10]) | ((unsigned)f2bf(acc[11]) << 16));
        o1.z = (int)((unsigned)f2bf(acc[12]) | ((unsigned)f2bf(acc[13]) << 16));
        o1.w = (int)((unsigned)f2bf(acc[14]) | ((unsigned)f2bf(acc[15]) << 16));
        *(int4*)&out[(size_t)node * 128 + fl * 16] = o0;
        *(int4*)&out[(size_t)node * 128 + fl * 16 + 8] = o1;
    }
}

// ---------------- bf16 MFMA GEMM, 128x128 tiles, dbuf, 8 waves (2x4 of 64x32) ----------------
// grid (ceil(M/128), 2): bn = blockIdx.y*128. global_load_lds width=16 into LINEAR LDS
// (LDT=32), double-buffered: STAGE(next) before compute(cur), one barrier/step.
// Verified frag layouts (learn_hip m89/m91/m120).

__global__ __launch_bounds__(512, 2) void gemm1_mfma_bias_relu(
        const unsigned short* __restrict__ A,    // [M][128] bf16
        const unsigned short* __restrict__ Bt,   // [256][128] bf16
        const float* __restrict__ bias,          // [256] fp32
        unsigned char* __restrict__ C, int M) {  // [M][256] fp8 e4m3
    constexpr int K = FDIM, Nc = HDIM, LDT = 32;
    __shared__ unsigned short As[2][128 * LDT];  // 8KB per buffer
    __shared__ unsigned short Bs[2][128 * LDT];
    int tid = threadIdx.x;
    int lane = tid & 63, wave = tid >> 6;
    int wm = (wave >> 2) * 64;                   // 0 | 64
    int wn2 = (wave & 3) * 32;                   // 0,32,64,96
    int bm = blockIdx.x * 128;
    int bn = blockIdx.y * 128;
    int l15 = lane & 15, quad = lane >> 4;
    int srow = tid >> 2, sq = (tid & 3) * 8;     // staging: row 0..127, k-subchunk

    floatx4 zero = {0.f, 0.f, 0.f, 0.f};
    floatx4 acc[4][2];
    #pragma unroll
    for (int s = 0; s < 4; ++s)
        #pragma unroll
        for (int t = 0; t < 2; ++t) acc[s][t] = zero;

    gload16(&A[(size_t)(bm + srow) * K + sq], &As[0][wave * 512]);
    gload16(&Bt[(size_t)(bn + srow) * K + sq], &Bs[0][wave * 512]);
    __syncthreads();
    int cur = 0;
    for (int k0 = 0; k0 < K; k0 += 32) {
        if (k0 + 32 < K) {   // stage next K-step into the other buffer
            gload16(&A[(size_t)(bm + srow) * K + k0 + 32 + sq], &As[cur ^ 1][wave * 512]);
            gload16(&Bt[(size_t)(bn + srow) * K + k0 + 32 + sq], &Bs[cur ^ 1][wave * 512]);
        }
        short8 af[4], bf[2];
        #pragma unroll
        for (int s = 0; s < 4; ++s)
            af[s] = *(const short8*)&As[cur][(wm + s * 16 + l15) * LDT + quad * 8];
        #pragma unroll
        for (int t = 0; t < 2; ++t)
            bf[t] = *(const short8*)&Bs[cur][(wn2 + t * 16 + l15) * LDT + quad * 8];
        #pragma unroll
        for (int s = 0; s < 4; ++s)
            #pragma unroll
            for (int t = 0; t < 2; ++t)
                acc[s][t] = __builtin_amdgcn_mfma_f32_16x16x32_bf16(af[s], bf[t], acc[s][t], 0, 0, 0);
        __syncthreads();                          // drains stage vmcnt + LDS reads
        cur ^= 1;
    }
    #pragma unroll
    for (int s = 0; s < 4; ++s) {
        int row0 = bm + wm + s * 16 + quad * 4;
        #pragma unroll
        for (int t = 0; t < 2; ++t) {
            int col = bn + wn2 + t * 16 + l15;
            float bb = bias[col];
            #pragma unroll
            for (int r = 0; r < 4; ++r) {
                int row = row0 + r;
                if (row < M)
                    C[(size_t)row * Nc + col] = enc8(fmaxf(acc[s][t][r] + bb, 0.f));
            }
        }
    }
}

// GEMM2 fused with mean-pool numerator. R19 epilogue: per-graph LDS reduction
// (part[ngr][128] via LDS atomics, reusing staging LDS), then ngr*128 global atomics
// per block instead of 4096. Fallback to direct atomics if ngr > 8.
__global__ __launch_bounds__(512, 2) void gemm2_pool(
        const unsigned short* __restrict__ A,    // [M][256] bf16 (a1b)
        const unsigned short* __restrict__ Bt,   // [256][256] bf16
        const float* __restrict__ bias,          // [256] fp32
        const int* __restrict__ batch,           // [M] sorted graph ids
        float* __restrict__ pool, int M) {       // [G][256] fp32, pre-zeroed
    constexpr int K = HDIM, Nc = HDIM, LDT = 32;
    constexpr int NGR_CAP = 8;
    __shared__ unsigned short As[2][128 * LDT];
    __shared__ unsigned short Bs[2][128 * LDT];
    int tid = threadIdx.x;
    int lane = tid & 63, wave = tid >> 6;
    int wm = (wave >> 2) * 64;
    int wn2 = (wave & 3) * 32;
    int bm = blockIdx.x * 128;
    int bn = blockIdx.y * 128;
    int l15 = lane & 15, quad = lane >> 4;
    int srow = tid >> 2, sq = (tid & 3) * 8;

    floatx4 zero = {0.f, 0.f, 0.f, 0.f};
    floatx4 acc[4][2];
    #pragma unroll
    for (int s = 0; s < 4; ++s)
        #pragma unroll
        for (int t = 0; t < 2; ++t) acc[s][t] = zero;

    gload16(&A[(size_t)(bm + srow) * K + sq], &As[0][wave * 512]);
    gload16(&Bt[(size_t)(bn + srow) * K + sq], &Bs[0][wave * 512]);
    __syncthreads();
    int cur = 0;
    for (int k0 = 0; k0 < K; k0 += 32) {
        if (k0 + 32 < K) {
            gload16(&A[(size_t)(bm + srow) * K + k0 + 32 + sq], &As[cur ^ 1][wave * 512]);
            gload16(&Bt[(size_t)(bn + srow) * K + k0 + 32 + sq], &Bs[cur ^ 1][wave * 512]);
        }
        short8 af[4], bf[2];
        #pragma unroll
        for (int s = 0; s < 4; ++s)
            af[s] = *(const short8*)&As[cur][(wm + s * 16 + l15) * LDT + quad * 8];
        #pragma unroll
        for (int t = 0; t < 2; ++t)
            bf[t] = *(const short8*)&Bs[cur][(wn2 + t * 16 + l15) * LDT + quad * 8];
        #pragma unroll
        for (int s = 0; s < 4; ++s)
            #pragma unroll
            for (int t = 0; t < 2; ++t)
                acc[s][t] = __builtin_amdgcn_mfma_f32_16x16x32_bf16(af[s], bf[t], acc[s][t], 0, 0, 0);
        __syncthreads();
        cur ^= 1;
    }
    // ---- R19 epilogue ----
    float* part = (float*)&As[0][0];            // NGR_CAP*128 floats = 4KB
    int lastRow = min(bm + 127, M - 1);
    int gfirst = batch[bm];
    int glast = batch[lastRow];
    int ngr = glast - gfirst + 1;
    if (ngr <= NGR_CAP) {
        for (int i = tid; i < ngr * 128; i += 512) part[i] = 0.f;
        __syncthreads();
        #pragma unroll
        for (int s = 0; s < 4; ++s) {
            int row0 = bm + wm + s * 16 + quad * 4;
            if (row0 >= M) continue;
            int gA = batch[row0];
            bool full = (row0 + 3 < M);
            bool same = full && (batch[row0 + 3] == gA);
            #pragma unroll
            for (int t = 0; t < 2; ++t) {
                int colL = wn2 + t * 16 + l15;
                float bb = bias[bn + colL];
                if (same) {
                    float v = fmaxf(acc[s][t][0] + bb, 0.f) + fmaxf(acc[s][t][1] + bb, 0.f)
                            + fmaxf(acc[s][t][2] + bb, 0.f) + fmaxf(acc[s][t][3] + bb, 0.f);
                    atomicAdd(&part[(gA - gfirst) * 128 + colL], v);
                } else {
                    #pragma unroll
                    for (int r = 0; r < 4; ++r) {
                        int row = row0 + r;
                        if (row < M) {
                            float v = fmaxf(acc[s][t][r] + bb, 0.f);
                            atomicAdd(&part[(batch[row] - gfirst) * 128 + colL], v);
                        }
                    }
                }
            }
        }
        __syncthreads();
        for (int i = tid; i < ngr * 128; i += 512) {
            float v = part[i];
            if (v != 0.f)
                atomicAdd(&pool[(size_t)(gfirst + (i >> 7)) * Nc + bn + (i & 127)], v);
        }
    } else {
        #pragma unroll
        for (int s = 0; s < 4; ++s) {
            int row0 = bm + wm + s * 16 + quad * 4;
            if (row0 >= M) continue;
            #pragma unroll
            for (int t = 0; t < 2; ++t) {
                int col = bn + wn2 + t * 16 + l15;
                float bb = bias[col];
                #pragma unroll
                for (int r = 0; r < 4; ++r) {
                    int row = row0 + r;
                    if (row < M) {
                        float v = fmaxf(acc[s][t][r] + bb, 0.f);
                        atomicAdd(&pool[(size_t)batch[row] * Nc + col], v);
                    }
                }
            }
        }
    }
}

// ---------------- head: one block per graph, reads pooled sums ----------------

__device__ __forceinline__ int lower_bound_i(const int* __restrict__ a, int n, int v) {
    int lo = 0, hi = n;
    while (lo < hi) {
        int mid = (lo + hi) >> 1;
        if (a[mid] < v) lo = mid + 1; else hi = mid;
    }
    return lo;
}

__global__ __launch_bounds__(256) void head_kernel(const float* __restrict__ pool,
                                                   const int* __restrict__ batch,
                                                   const float* __restrict__ num_atoms,
                                                   const float* __restrict__ W3, const float* __restrict__ b3,
                                                   const float* __restrict__ W4, const float* __restrict__ b4,
                                                   float* __restrict__ out, int n) {
    int g = blockIdx.x;
    int tid = threadIdx.x;
    __shared__ int s_lo, s_hi;
    if (tid == 0) {
        s_lo = lower_bound_i(batch, n, g);
        s_hi = lower_bound_i(batch, n, g + 1);
    }
    __syncthreads();
    float cnt = (float)(s_hi - s_lo);

    __shared__ float zin[HDIM + 1];
    __shared__ float z[32];
    zin[tid] = pool[(size_t)g * HDIM + tid] / fmaxf(cnt, 1.0f);
    if (tid == 0) zin[HDIM] = num_atoms[g];
    __syncthreads();
    if (tid < 32) {
        float a = b3[tid];
        for (int k = 0; k < HDIM + 1; ++k) a = fmaf(zin[k], W3[k * 32 + tid], a);
        z[tid] = fmaxf(a, 0.f);
    }
    __syncthreads();
    if (tid < 4) {
        float a = b4[tid];
        #pragma unroll
        for (int k = 0; k < 32; ++k) a = fmaf(z[k], W4[k * 4 + tid], a);
        out[g * 4 + tid] = a;
    }
}

// ---------------- launch ----------------

extern "C" void kernel_launch(void* const* d_in, const int* in_sizes, int n_in,
                              void* d_out, int out_size, void* d_ws, size_t ws_size,
                              hipStream_t stream) {
    const float* x         = (const float*)d_in[0];
    const int*   edge_idx  = (const int*)d_in[1];
    const int*   batch     = (const int*)d_in[2];
    const float* num_atoms = (const float*)d_in[3];
    const float* W1 = (const float*)d_in[4];
    const float* b1 = (const float*)d_in[5];
    const float* W2 = (const float*)d_in[6];
    const float* b2 = (const float*)d_in[7];
    const float* W3 = (const float*)d_in[8];
    const float* b3 = (const float*)d_in[9];
    const float* W4 = (const float*)d_in[10];
    const float* b4 = (const float*)d_in[11];
    float* out = (float*)d_out;

    const int n = NN, e = EE;
    const int* e_src = edge_idx;
    const int* e_dst = edge_idx + e;

    // workspace (256B aligned). Lifetime aliasing:
    //   x_f8 (6.4MB): [N,128] fp8 (cast_hist out, dead after agg128).
    //   P (25.6MB): a0b [N,128]bf16 (dead after gemm1); whole P reused as a1b [N,256]bf16.
    //   Q (12.8MB): h1f8 [N,256]fp8 (gemm1 out, dead after agg256). Absorbs GEMM
    //               A-staging over-reads past row M.
    //   pool (512KB): [G,256] fp32 pooled sums (gemm2_pool out -> head).
    char* ws = (char*)d_ws;
    size_t off = 0;
    auto carve = [&](size_t bytes) -> void* {
        void* p = ws + off;
        off = (off + bytes + 255) & ~(size_t)255;
        return p;
    };
    int*   deg_i    = (int*)carve((size_t)n * 4);
    int*   row_off  = (int*)carve((size_t)(n + 1) * 4);
    int*   blk_sums = (int*)carve((size_t)256 * 4);
    float* dinv     = (float*)carve((size_t)n * 4);
    int*   epos     = (int*)carve((size_t)e * 4);
    unsigned short* W1t = (unsigned short*)carve((size_t)FDIM * HDIM * 2);
    unsigned short* W2t = (unsigned short*)carve((size_t)HDIM * HDIM * 2);
    int2*  csr      = (int2*)carve((size_t)e * 8);
    unsigned char* x_f8 = (unsigned char*)carve((size_t)n * FDIM);
    unsigned short* P = (unsigned short*)carve((size_t)n * HDIM * 2);
    unsigned char*  Q = (unsigned char*)carve((size_t)n * HDIM);
    float* pool     = (float*)carve((size_t)GG * HDIM * 4);
    unsigned short* a0b  = P;                       // [N,128] bf16
    unsigned short* a1b  = P;                       // [N,256] bf16 (a0b dead)
    unsigned char*  h1f8 = Q;                       // [N,256] fp8 e4m3
    (void)ws_size; (void)n_in; (void)in_sizes; (void)out_size;

    // deg must be zero before cast_hist's atomic histogram
    hipMemsetAsync(deg_i, 0, (size_t)n * 4, stream);
    // cast x (fp8) + W transposes + zero pool + hist(+epos): one dispatch
    cast_hist<<<(CAST_TOTAL + 255) / 256, 256, 0, stream>>>(
        x, x_f8, W1, W1t, W2, W2t, pool, e_dst, deg_i, epos, e);
    scan_part<<<SCAN_NB, 256, 0, stream>>>(deg_i, row_off, blk_sums, dinv, n);
    scan_sums<<<1, 256, 0, stream>>>(blk_sums, SCAN_NB);
    scatter_kernel<<<1024, 256, 0, stream>>>(e_src, e_dst, row_off, blk_sums, epos, dinv, csr, e);

    dim3 gemm_grid((n + 127) / 128, 2);
    // L1: a0 = agg(x_f8) bf16; h1f8 = fp8(relu(a0 @ W1 + b1))
    gcn_agg128_fp8<<<(n + 3) / 4, 256, 0, stream>>>(x_f8, row_off, blk_sums, csr, dinv, a0b, n);
    gemm1_mfma_bias_relu<<<gemm_grid, 512, 0, stream>>>(a0b, W1t, b1, h1f8, n);
    // L2: a1 = agg(h1f8) bf16; pool += segsum(relu(a1 @ W2 + b2))
    gcn_agg256_fp8<<<(n + 3) / 4, 256, 0, stream>>>(h1f8, row_off, blk_sums, csr, dinv, a1b, n);
    gemm2_pool<<<gemm_grid, 512, 0, stream>>>(a1b, W2t, b2, batch, pool, n);
    // head
    head_kernel<<<GG, 256, 0, stream>>>(pool, batch, num_atoms, W3, b3, W4, b4, out, n);
}

// Round 15
// 284.738 us; speedup vs baseline: 1.0547x; 1.0036x over previous
//
#include <hip/hip_runtime.h>
#include <hip/hip_bf16.h>
#include <hip/hip_fp8.h>

// GNN: 2-layer GCN (N=50000, E=800000, F=128, H=256) + mean-pool (G=512) + MLP head (257->32->4)
// Key identity: segment_sum((xW)[src]*norm) == (segment_sum(x[src]*norm)) @ W  (GCN agg is linear)
//   prep:  memset(deg) -> cast_hist (HIST FIRST, then x->FP8, W transpose, zero pool) ->
//          scan_part -> scan_sums -> scatter (prefix applied inline)
//   L1: agg128_fp8(x_f8) -> a0 bf16; h1 = relu(a0 @ W1 + b1) -> FP8 e4m3  [MFMA dbuf tiles]
//   L2: agg256_fp8(h1) -> a1 bf16; gemm2_pool: relu(a1 @ W2 + b2) pooled into pool[G,256]
//   head: per-graph block: mean + 257->32->4 MLP
// R8/R9: agg at 8-XCD compulsory BYTES floor. R15: agg+GEMM fusion refuted (TLP loss).
// R16: atomic-free scatter. R17/R20: fp8 gather tables (absmax UNCHANGED). R18: gemm2
//   invariant under occupancy/dbuf => atomic-bound. R19: per-graph LDS pool reduction.
// R21: cast+hist merged but hist range at TAIL of index space -> blocks dispatch last ->
//   serialized (43us = cast+hist). Profile exposed hist as ~33us hidden atomic cost.
// R22: hist range FIRST (idx < EE, 1 edge/thread): hist blocks dispatch first, atomic
//   round-trips overlap with cast streaming behind. Expect max() not sum().

#define NN 50000
#define EE 800000
#define FDIM 128
#define HDIM 256
#define GG 512
#define SCAN_NB ((NN + 255) / 256)

typedef __attribute__((ext_vector_type(8))) short short8;     // 8 bf16 = 4 VGPRs (MFMA A/B frag)
typedef __attribute__((ext_vector_type(4))) float floatx4;    // MFMA C/D frag
typedef __attribute__((ext_vector_type(2))) float floatx2;

__device__ __forceinline__ unsigned short f2bf(float f) {   // RNE
    unsigned u = __float_as_uint(f);
    return (unsigned short)((u + 0x7FFF + ((u >> 16) & 1)) >> 16);
}
__device__ __forceinline__ float bflo(unsigned v) { return __uint_as_float(v << 16); }
__device__ __forceinline__ float bfhi(unsigned v) { return __uint_as_float(v & 0xFFFF0000u); }

// fp8 e4m3 (OCP on gfx950) encode/decode via HW cvt; fallback to hip_fp8 type.
__device__ __forceinline__ unsigned char enc8(float v) {
#if defined(__has_builtin) && __has_builtin(__builtin_amdgcn_cvt_pk_fp8_f32)
    return (unsigned char)(__builtin_amdgcn_cvt_pk_fp8_f32(v, v, 0, false) & 0xFF);
#else
    __hip_fp8_e4m3 q(v);
    return (unsigned char)q.__x;
#endif
}
__device__ __forceinline__ unsigned pack4_fp8(float a, float b, float c, float d) {
#if defined(__has_builtin) && __has_builtin(__builtin_amdgcn_cvt_pk_fp8_f32)
    unsigned lo = (unsigned)__builtin_amdgcn_cvt_pk_fp8_f32(a, b, 0, false) & 0xFFFFu;
    unsigned hi = (unsigned)__builtin_amdgcn_cvt_pk_fp8_f32(c, d, 0, false) & 0xFFFFu;
    return lo | (hi << 16);
#else
    return (unsigned)enc8(a) | ((unsigned)enc8(b) << 8) |
           ((unsigned)enc8(c) << 16) | ((unsigned)enc8(d) << 24);
#endif
}
__device__ __forceinline__ void dec4(int d, float* f) {   // 4 fp8 bytes -> 4 floats
#if defined(__has_builtin) && __has_builtin(__builtin_amdgcn_cvt_pk_f32_fp8)
    floatx2 lo = __builtin_amdgcn_cvt_pk_f32_fp8(d, false);
    floatx2 hi = __builtin_amdgcn_cvt_pk_f32_fp8(d, true);
    f[0] = lo.x; f[1] = lo.y; f[2] = hi.x; f[3] = hi.y;
#else
    unsigned u = (unsigned)d;
    #pragma unroll
    for (int i = 0; i < 4; ++i) {
        __hip_fp8_e4m3 t; t.__x = (__hip_fp8_storage_t)((u >> (8 * i)) & 0xFF);
        f[i] = (float)t;
    }
#endif
}

// async global->LDS, 16B per lane. lds ptr must be wave-uniform (HW adds lane*16).
__device__ __forceinline__ void gload16(const void* g, void* l) {
    __builtin_amdgcn_global_load_lds((const __attribute__((address_space(1))) void*)g,
                                     (__attribute__((address_space(3))) void*)l, 16, 0, 0);
}

// ---------------- prep kernels ----------------

// merged: HIST (first: 1 edge/thread, blocks dispatch earliest, atomic latency overlaps
// the streaming ranges behind) + x fp32->fp8 cast + W1/W2 transpose-cast + zero pool.
// deg pre-zeroed by memset.
#define XCHUNKS (NN * FDIM / 4)            // 1,600,000 float4 groups
#define CAST_TOTAL (EE + XCHUNKS + FDIM * HDIM + HDIM * HDIM + GG * HDIM / 4)
__global__ __launch_bounds__(256) void cast_hist(const float* __restrict__ x,
                                                 unsigned char* __restrict__ x_f8,
                                                 const float* __restrict__ W1,
                                                 unsigned short* __restrict__ W1t,
                                                 const float* __restrict__ W2,
                                                 unsigned short* __restrict__ W2t,
                                                 float* __restrict__ pool,
                                                 const int* __restrict__ dst,
                                                 int* __restrict__ deg,
                                                 int* __restrict__ epos) {
    int idx = blockIdx.x * 256 + threadIdx.x;
    if (idx < EE) {                      // hist + per-edge ordinal (latency phase, FIRST)
        epos[idx] = atomicAdd(&deg[dst[idx]], 1);
        return;
    }
    int r = idx - EE;
    if (r < XCHUNKS) {
        int i = r * 4;
        float4 v = *(const float4*)&x[i];
        *(unsigned*)&x_f8[i] = pack4_fp8(v.x, v.y, v.z, v.w);
        return;
    }
    r -= XCHUNKS;
    if (r < FDIM * HDIM) {               // W1t[n][k] = bf16(W1[k][n]), K=128, Nc=256
        int nn = r / FDIM, k = r - nn * FDIM;
        W1t[r] = f2bf(W1[(size_t)k * HDIM + nn]);
        return;
    }
    r -= FDIM * HDIM;
    if (r < HDIM * HDIM) {               // W2t[n][k] = bf16(W2[k][n]), K=256, Nc=256
        int nn = r / HDIM, k = r - nn * HDIM;
        W2t[r] = f2bf(W2[(size_t)k * HDIM + nn]);
        return;
    }
    r -= HDIM * HDIM;
    if (r < GG * HDIM / 4) {             // zero pool
        float4 z = {0.f, 0.f, 0.f, 0.f};
        *(float4*)&pool[r * 4] = z;
    }
}

__global__ __launch_bounds__(256) void scan_part(const int* __restrict__ deg,
                                                 int* __restrict__ row_off,
                                                 int* __restrict__ blk_sums,
                                                 float* __restrict__ dinv, int n) {
    __shared__ int s[256];
    int tid = threadIdx.x;
    int i = blockIdx.x * 256 + tid;
    int v = (i < n) ? deg[i] : 0;
    if (i < n) dinv[i] = rsqrtf((float)v + 1.0f);
    s[tid] = v;
    __syncthreads();
    #pragma unroll
    for (int off = 1; off < 256; off <<= 1) {
        int t = (tid >= off) ? s[tid - off] : 0;
        __syncthreads();
        s[tid] += t;
        __syncthreads();
    }
    if (i < n) row_off[i] = s[tid] - v;
    if (tid == 255) blk_sums[blockIdx.x] = s[255];
}

__global__ __launch_bounds__(256) void scan_sums(int* __restrict__ blk_sums, int nb) {
    __shared__ int s[256];
    int tid = threadIdx.x;
    int v = (tid < nb) ? blk_sums[tid] : 0;
    s[tid] = v;
    __syncthreads();
    #pragma unroll
    for (int off = 1; off < 256; off <<= 1) {
        int t = (tid >= off) ? s[tid - off] : 0;
        __syncthreads();
        s[tid] += t;
        __syncthreads();
    }
    if (tid < nb) blk_sums[tid] = s[tid] - v;
}

// atomic-free scatter; final offset = row_off[d] + blk_sums[d>>8] + epos[i]
__global__ void scatter_kernel(const int* __restrict__ src, const int* __restrict__ dst,
                               const int* __restrict__ row_off, const int* __restrict__ blk_sums,
                               const int* __restrict__ epos,
                               const float* __restrict__ dinv,
                               int2* __restrict__ csr, int e) {
    int i = blockIdx.x * blockDim.x + threadIdx.x;
    int stride = gridDim.x * blockDim.x;
    for (; i < e; i += stride) {
        int s = src[i], d = dst[i];
        int pos = row_off[d] + blk_sums[d >> 8] + epos[i];
        csr[pos] = make_int2(s, __float_as_int(dinv[s] * dinv[d]));
    }
}

// ---------------- GCN aggregation ----------------
// out[d] = sum_e in[src_e]*w_e + in[d]*dinv[d]^2 ; fp8 gather tables, fp32 accum, bf16 out.
// wave-per-node, dwordx4 (16B) gathers, wave split across edge slots.
// Row ranges computed inline: off(i) = row_off[i] + blk_sums[i>>8]; off(n) = EE.

__device__ __forceinline__ void fma16(const int4& g, float wgt, float* acc) {
    float f[16];
    dec4(g.x, f); dec4(g.y, f + 4); dec4(g.z, f + 8); dec4(g.w, f + 12);
    #pragma unroll
    for (int i = 0; i < 16; ++i) acc[i] = fmaf(f[i], wgt, acc[i]);
}

__device__ __forceinline__ int row_begin(const int* ro, const int* bs, int i) {
    return ro[i] + bs[i >> 8];
}

// L2 aggregation over fp8 h1 table: row = 256B; 16 lanes x 16B; 4 edge slots; 8 edges/iter.
__global__ __launch_bounds__(256) void gcn_agg256_fp8(const unsigned char* __restrict__ in,
                                                      const int* __restrict__ row_off,
                                                      const int* __restrict__ blk_sums,
                                                      const int2* __restrict__ csr,
                                                      const float* __restrict__ dinv,
                                                      unsigned short* __restrict__ out, int n) {
    int wave = threadIdx.x >> 6;
    int lane = threadIdx.x & 63;
    int node = blockIdx.x * 4 + wave;
    if (node >= n) return;
    int sub = lane >> 4;          // edge slot 0..3
    int fl  = lane & 15;          // 16B chunk within 256B row
    float di = dinv[node];
    float w0 = (sub == 0) ? di * di : 0.f;

    float acc[16];
    {   // self term
        int4 sv = *(const int4*)&in[(size_t)node * 256 + fl * 16];
        float f[16];
        dec4(sv.x, f); dec4(sv.y, f + 4); dec4(sv.z, f + 8); dec4(sv.w, f + 12);
        #pragma unroll
        for (int i = 0; i < 16; ++i) acc[i] = f[i] * w0;
    }

    int beg = __builtin_amdgcn_readfirstlane(row_begin(row_off, blk_sums, node));
    int end = __builtin_amdgcn_readfirstlane(
        (node + 1 < n) ? row_begin(row_off, blk_sums, node + 1) : EE);
    int cnt = end - beg;
    if (cnt > 0) {
        int nIter = (cnt + 7) >> 3;                    // 8 edges / iter (2 gathers)
        int base = beg;
        int last = end - 1;
        int i0 = base + sub, i1 = base + 4 + sub;
        int2 c0 = csr[i0 < end ? i0 : last];
        int2 c1 = csr[i1 < end ? i1 : last];
        for (int it = 0; it < nIter; ++it) {
            int4 g0 = *(const int4*)&in[(size_t)c0.x * 256 + fl * 16];
            int4 g1 = *(const int4*)&in[(size_t)c1.x * 256 + fl * 16];
            float we0 = (base + sub < end) ? __int_as_float(c0.y) : 0.f;
            float we1 = (base + 4 + sub < end) ? __int_as_float(c1.y) : 0.f;
            int nb = base + 8;
            int j0 = nb + sub, j1 = nb + 4 + sub;
            int2 n0 = csr[j0 < end ? j0 : last];
            int2 n1 = csr[j1 < end ? j1 : last];
            fma16(g0, we0, acc); fma16(g1, we1, acc);
            c0 = n0; c1 = n1; base = nb;
        }
    }
    // combine 4 edge-slots (lanes sharing fl differ in bits 4..5)
    #pragma unroll
    for (int i = 0; i < 16; ++i) {
        acc[i] += __shfl_xor(acc[i], 16);
        acc[i] += __shfl_xor(acc[i], 32);
    }
    if (sub == 0) {
        int4 o0, o1;
        o0.x = (int)((unsigned)f2bf(acc[0])  | ((unsigned)f2bf(acc[1])  << 16));
        o0.y = (int)((unsigned)f2bf(acc[2])  | ((unsigned)f2bf(acc[3])  << 16));
        o0.z = (int)((unsigned)f2bf(acc[4])  | ((unsigned)f2bf(acc[5])  << 16));
        o0.w = (int)((unsigned)f2bf(acc[6])  | ((unsigned)f2bf(acc[7])  << 16));
        o1.x = (int)((unsigned)f2bf(acc[8])  | ((unsigned)f2bf(acc[9])  << 16));
        o1.y = (int)((unsigned)f2bf(acc[10]) | ((unsigned)f2bf(acc[11]) << 16));
        o1.z = (int)((unsigned)f2bf(acc[12]) | ((unsigned)f2bf(acc[13]) << 16));
        o1.w = (int)((unsigned)f2bf(acc[14]) | ((unsigned)f2bf(acc[15]) << 16));
        *(int4*)&out[(size_t)node * 256 + fl * 16] = o0;
        *(int4*)&out[(size_t)node * 256 + fl * 16 + 8] = o1;
    }
}

// L1 aggregation over fp8 x table: row = 128B; 8 lanes x 16B; 8 edge slots; 16 edges/iter.
__global__ __launch_bounds__(256) void gcn_agg128_fp8(const unsigned char* __restrict__ in,
                                                      const int* __restrict__ row_off,
                                                      const int* __restrict__ blk_sums,
                                                      const int2* __restrict__ csr,
                                                      const float* __restrict__ dinv,
                                                      unsigned short* __restrict__ out, int n) {
    int wave = threadIdx.x >> 6;
    int lane = threadIdx.x & 63;
    int node = blockIdx.x * 4 + wave;
    if (node >= n) return;
    int sub = lane >> 3;          // edge slot 0..7
    int fl  = lane & 7;           // 16B chunk within 128B row
    float di = dinv[node];
    float w0 = (sub == 0) ? di * di : 0.f;

    float acc[16];
    {   // self term
        int4 sv = *(const int4*)&in[(size_t)node * 128 + fl * 16];
        float f[16];
        dec4(sv.x, f); dec4(sv.y, f + 4); dec4(sv.z, f + 8); dec4(sv.w, f + 12);
        #pragma unroll
        for (int i = 0; i < 16; ++i) acc[i] = f[i] * w0;
    }

    int beg = __builtin_amdgcn_readfirstlane(row_begin(row_off, blk_sums, node));
    int end = __builtin_amdgcn_readfirstlane(
        (node + 1 < n) ? row_begin(row_off, blk_sums, node + 1) : EE);
    int cnt = end - beg;
    if (cnt > 0) {
        int nIter = (cnt + 15) >> 4;                   // 16 edges / iter (2 gathers)
        int base = beg;
        int last = end - 1;
        int i0 = base + sub, i1 = base + 8 + sub;
        int2 c0 = csr[i0 < end ? i0 : last];
        int2 c1 = csr[i1 < end ? i1 : last];
        for (int it = 0; it < nIter; ++it) {
            int4 g0 = *(const int4*)&in[(size_t)c0.x * 128 + fl * 16];
            int4 g1 = *(const int4*)&in[(size_t)c1.x * 128 + fl * 16];
            float we0 = (base + sub < end) ? __int_as_float(c0.y) : 0.f;
            float we1 = (base + 8 + sub < end) ? __int_as_float(c1.y) : 0.f;
            int nb = base + 16;
            int j0 = nb + sub, j1 = nb + 8 + sub;
            int2 n0 = csr[j0 < end ? j0 : last];
            int2 n1 = csr[j1 < end ? j1 : last];
            fma16(g0, we0, acc); fma16(g1, we1, acc);
            c0 = n0; c1 = n1; base = nb;
        }
    }
    // combine 8 edge-slots (lanes sharing fl differ in bits 3..5)
    #pragma unroll
    for (int i = 0; i < 16; ++i) {
        acc[i] += __shfl_xor(acc[i], 8);
        acc[i] += __shfl_xor(acc[i], 16);
        acc[i] += __shfl_xor(acc[i], 32);
    }
    if (sub == 0) {
        int4 o0, o1;
        o0.x = (int)((unsigned)f2bf(acc[0])  | ((unsigned)f2bf(acc[1])  << 16));
        o0.y = (int)((unsigned)f2bf(acc[2])  | ((unsigned)f2bf(acc[3])  << 16));
        o0.z = (int)((unsigned)f2bf(acc[4])  | ((unsigned)f2bf(acc[5])  << 16));
        o0.w = (int)((unsigned)f2bf(acc[6])  | ((unsigned)f2bf(acc[7])  << 16));
        o1.x = (int)((unsigned)f2bf(acc[8])  | ((unsigned)f2bf(acc[9])  << 16));
        o1.y = (int)((unsigned)f2bf(acc[10]) | ((unsigned)f2bf(acc[11]) << 16));
        o1.z = (int)((unsigned)f2bf(acc[12]) | ((unsigned)f2bf(acc[13]) << 16));
        o1.w = (int)((unsigned)f2bf(acc[14]) | ((unsigned)f2bf(acc[15]) << 16));
        *(int4*)&out[(size_t)node * 128 + fl * 16] = o0;
        *(int4*)&out[(size_t)node * 128 + fl * 16 + 8] = o1;
    }
}

// ---------------- bf16 MFMA GEMM, 128x128 tiles, dbuf, 8 waves (2x4 of 64x32) ----------------
// grid (ceil(M/128), 2): bn = blockIdx.y*128. global_load_lds width=16 into LINEAR LDS
// (LDT=32), double-buffered: STAGE(next) before compute(cur), one barrier/step.
// Verified frag layouts (learn_hip m89/m91/m120).

__global__ __launch_bounds__(512, 2) void gemm1_mfma_bias_relu(
        const unsigned short* __restrict__ A,    // [M][128] bf16
        const unsigned short* __restrict__ Bt,   // [256][128] bf16
        const float* __restrict__ bias,          // [256] fp32
        unsigned char* __restrict__ C, int M) {  // [M][256] fp8 e4m3
    constexpr int K = FDIM, Nc = HDIM, LDT = 32;
    __shared__ unsigned short As[2][128 * LDT];  // 8KB per buffer
    __shared__ unsigned short Bs[2][128 * LDT];
    int tid = threadIdx.x;
    int lane = tid & 63, wave = tid >> 6;
    int wm = (wave >> 2) * 64;                   // 0 | 64
    int wn2 = (wave & 3) * 32;                   // 0,32,64,96
    int bm = blockIdx.x * 128;
    int bn = blockIdx.y * 128;
    int l15 = lane & 15, quad = lane >> 4;
    int srow = tid >> 2, sq = (tid & 3) * 8;     // staging: row 0..127, k-subchunk

    floatx4 zero = {0.f, 0.f, 0.f, 0.f};
    floatx4 acc[4][2];
    #pragma unroll
    for (int s = 0; s < 4; ++s)
        #pragma unroll
        for (int t = 0; t < 2; ++t) acc[s][t] = zero;

    gload16(&A[(size_t)(bm + srow) * K + sq], &As[0][wave * 512]);
    gload16(&Bt[(size_t)(bn + srow) * K + sq], &Bs[0][wave * 512]);
    __syncthreads();
    int cur = 0;
    for (int k0 = 0; k0 < K; k0 += 32) {
        if (k0 + 32 < K) {   // stage next K-step into the other buffer
            gload16(&A[(size_t)(bm + srow) * K + k0 + 32 + sq], &As[cur ^ 1][wave * 512]);
            gload16(&Bt[(size_t)(bn + srow) * K + k0 + 32 + sq], &Bs[cur ^ 1][wave * 512]);
        }
        short8 af[4], bf[2];
        #pragma unroll
        for (int s = 0; s < 4; ++s)
            af[s] = *(const short8*)&As[cur][(wm + s * 16 + l15) * LDT + quad * 8];
        #pragma unroll
        for (int t = 0; t < 2; ++t)
            bf[t] = *(const short8*)&Bs[cur][(wn2 + t * 16 + l15) * LDT + quad * 8];
        #pragma unroll
        for (int s = 0; s < 4; ++s)
            #pragma unroll
            for (int t = 0; t < 2; ++t)
                acc[s][t] = __builtin_amdgcn_mfma_f32_16x16x32_bf16(af[s], bf[t], acc[s][t], 0, 0, 0);
        __syncthreads();                          // drains stage vmcnt + LDS reads
        cur ^= 1;
    }
    #pragma unroll
    for (int s = 0; s < 4; ++s) {
        int row0 = bm + wm + s * 16 + quad * 4;
        #pragma unroll
        for (int t = 0; t < 2; ++t) {
            int col = bn + wn2 + t * 16 + l15;
            float bb = bias[col];
            #pragma unroll
            for (int r = 0; r < 4; ++r) {
                int row = row0 + r;
                if (row < M)
                    C[(size_t)row * Nc + col] = enc8(fmaxf(acc[s][t][r] + bb, 0.f));
            }
        }
    }
}

// GEMM2 fused with mean-pool numerator. R19 epilogue: per-graph LDS reduction
// (part[ngr][128] via LDS atomics, reusing staging LDS), then ngr*128 global atomics
// per block instead of 4096. Fallback to direct atomics if ngr > 8.
__global__ __launch_bounds__(512, 2) void gemm2_pool(
        const unsigned short* __restrict__ A,    // [M][256] bf16 (a1b)
        const unsigned short* __restrict__ Bt,   // [256][256] bf16
        const float* __restrict__ bias,          // [256] fp32
        const int* __restrict__ batch,           // [M] sorted graph ids
        float* __restrict__ pool, int M) {       // [G][256] fp32, pre-zeroed
    constexpr int K = HDIM, Nc = HDIM, LDT = 32;
    constexpr int NGR_CAP = 8;
    __shared__ unsigned short As[2][128 * LDT];
    __shared__ unsigned short Bs[2][128 * LDT];
    int tid = threadIdx.x;
    int lane = tid & 63, wave = tid >> 6;
    int wm = (wave >> 2) * 64;
    int wn2 = (wave & 3) * 32;
    int bm = blockIdx.x * 128;
    int bn = blockIdx.y * 128;
    int l15 = lane & 15, quad = lane >> 4;
    int srow = tid >> 2, sq = (tid & 3) * 8;

    floatx4 zero = {0.f, 0.f, 0.f, 0.f};
    floatx4 acc[4][2];
    #pragma unroll
    for (int s = 0; s < 4; ++s)
        #pragma unroll
        for (int t = 0; t < 2; ++t) acc[s][t] = zero;

    gload16(&A[(size_t)(bm + srow) * K + sq], &As[0][wave * 512]);
    gload16(&Bt[(size_t)(bn + srow) * K + sq], &Bs[0][wave * 512]);
    __syncthreads();
    int cur = 0;
    for (int k0 = 0; k0 < K; k0 += 32) {
        if (k0 + 32 < K) {
            gload16(&A[(size_t)(bm + srow) * K + k0 + 32 + sq], &As[cur ^ 1][wave * 512]);
            gload16(&Bt[(size_t)(bn + srow) * K + k0 + 32 + sq], &Bs[cur ^ 1][wave * 512]);
        }
        short8 af[4], bf[2];
        #pragma unroll
        for (int s = 0; s < 4; ++s)
            af[s] = *(const short8*)&As[cur][(wm + s * 16 + l15) * LDT + quad * 8];
        #pragma unroll
        for (int t = 0; t < 2; ++t)
            bf[t] = *(const short8*)&Bs[cur][(wn2 + t * 16 + l15) * LDT + quad * 8];
        #pragma unroll
        for (int s = 0; s < 4; ++s)
            #pragma unroll
            for (int t = 0; t < 2; ++t)
                acc[s][t] = __builtin_amdgcn_mfma_f32_16x16x32_bf16(af[s], bf[t], acc[s][t], 0, 0, 0);
        __syncthreads();
        cur ^= 1;
    }
    // ---- R19 epilogue ----
    float* part = (float*)&As[0][0];            // NGR_CAP*128 floats = 4KB
    int lastRow = min(bm + 127, M - 1);
    int gfirst = batch[bm];
    int glast = batch[lastRow];
    int ngr = glast - gfirst + 1;
    if (ngr <= NGR_CAP) {
        for (int i = tid; i < ngr * 128; i += 512) part[i] = 0.f;
        __syncthreads();
        #pragma unroll
        for (int s = 0; s < 4; ++s) {
            int row0 = bm + wm + s * 16 + quad * 4;
            if (row0 >= M) continue;
            int gA = batch[row0];
            bool full = (row0 + 3 < M);
            bool same = full && (batch[row0 + 3] == gA);
            #pragma unroll
            for (int t = 0; t < 2; ++t) {
                int colL = wn2 + t * 16 + l15;
                float bb = bias[bn + colL];
                if (same) {
                    float v = fmaxf(acc[s][t][0] + bb, 0.f) + fmaxf(acc[s][t][1] + bb, 0.f)
                            + fmaxf(acc[s][t][2] + bb, 0.f) + fmaxf(acc[s][t][3] + bb, 0.f);
                    atomicAdd(&part[(gA - gfirst) * 128 + colL], v);
                } else {
                    #pragma unroll
                    for (int r = 0; r < 4; ++r) {
                        int row = row0 + r;
                        if (row < M) {
                            float v = fmaxf(acc[s][t][r] + bb, 0.f);
                            atomicAdd(&part[(batch[row] - gfirst) * 128 + colL], v);
                        }
                    }
                }
            }
        }
        __syncthreads();
        for (int i = tid; i < ngr * 128; i += 512) {
            float v = part[i];
            if (v != 0.f)
                atomicAdd(&pool[(size_t)(gfirst + (i >> 7)) * Nc + bn + (i & 127)], v);
        }
    } else {
        #pragma unroll
        for (int s = 0; s < 4; ++s) {
            int row0 = bm + wm + s * 16 + quad * 4;
            if (row0 >= M) continue;
            #pragma unroll
            for (int t = 0; t < 2; ++t) {
                int col = bn + wn2 + t * 16 + l15;
                float bb = bias[col];
                #pragma unroll
                for (int r = 0; r < 4; ++r) {
                    int row = row0 + r;
                    if (row < M) {
                        float v = fmaxf(acc[s][t][r] + bb, 0.f);
                        atomicAdd(&pool[(size_t)batch[row] * Nc + col], v);
                    }
                }
            }
        }
    }
}

// ---------------- head: one block per graph, reads pooled sums ----------------

__device__ __forceinline__ int lower_bound_i(const int* __restrict__ a, int n, int v) {
    int lo = 0, hi = n;
    while (lo < hi) {
        int mid = (lo + hi) >> 1;
        if (a[mid] < v) lo = mid + 1; else hi = mid;
    }
    return lo;
}

__global__ __launch_bounds__(256) void head_kernel(const float* __restrict__ pool,
                                                   const int* __restrict__ batch,
                                                   const float* __restrict__ num_atoms,
                                                   const float* __restrict__ W3, const float* __restrict__ b3,
                                                   const float* __restrict__ W4, const float* __restrict__ b4,
                                                   float* __restrict__ out, int n) {
    int g = blockIdx.x;
    int tid = threadIdx.x;
    __shared__ int s_lo, s_hi;
    if (tid == 0) {
        s_lo = lower_bound_i(batch, n, g);
        s_hi = lower_bound_i(batch, n, g + 1);
    }
    __syncthreads();
    float cnt = (float)(s_hi - s_lo);

    __shared__ float zin[HDIM + 1];
    __shared__ float z[32];
    zin[tid] = pool[(size_t)g * HDIM + tid] / fmaxf(cnt, 1.0f);
    if (tid == 0) zin[HDIM] = num_atoms[g];
    __syncthreads();
    if (tid < 32) {
        float a = b3[tid];
        for (int k = 0; k < HDIM + 1; ++k) a = fmaf(zin[k], W3[k * 32 + tid], a);
        z[tid] = fmaxf(a, 0.f);
    }
    __syncthreads();
    if (tid < 4) {
        float a = b4[tid];
        #pragma unroll
        for (int k = 0; k < 32; ++k) a = fmaf(z[k], W4[k * 4 + tid], a);
        out[g * 4 + tid] = a;
    }
}

// ---------------- launch ----------------

extern "C" void kernel_launch(void* const* d_in, const int* in_sizes, int n_in,
                              void* d_out, int out_size, void* d_ws, size_t ws_size,
                              hipStream_t stream) {
    const float* x         = (const float*)d_in[0];
    const int*   edge_idx  = (const int*)d_in[1];
    const int*   batch     = (const int*)d_in[2];
    const float* num_atoms = (const float*)d_in[3];
    const float* W1 = (const float*)d_in[4];
    const float* b1 = (const float*)d_in[5];
    const float* W2 = (const float*)d_in[6];
    const float* b2 = (const float*)d_in[7];
    const float* W3 = (const float*)d_in[8];
    const float* b3 = (const float*)d_in[9];
    const float* W4 = (const float*)d_in[10];
    const float* b4 = (const float*)d_in[11];
    float* out = (float*)d_out;

    const int n = NN, e = EE;
    const int* e_src = edge_idx;
    const int* e_dst = edge_idx + e;

    // workspace (256B aligned). Lifetime aliasing:
    //   x_f8 (6.4MB): [N,128] fp8 (cast_hist out, dead after agg128).
    //   P (25.6MB): a0b [N,128]bf16 (dead after gemm1); whole P reused as a1b [N,256]bf16.
    //   Q (12.8MB): h1f8 [N,256]fp8 (gemm1 out, dead after agg256). Absorbs GEMM
    //               A-staging over-reads past row M.
    //   pool (512KB): [G,256] fp32 pooled sums (gemm2_pool out -> head).
    char* ws = (char*)d_ws;
    size_t off = 0;
    auto carve = [&](size_t bytes) -> void* {
        void* p = ws + off;
        off = (off + bytes + 255) & ~(size_t)255;
        return p;
    };
    int*   deg_i    = (int*)carve((size_t)n * 4);
    int*   row_off  = (int*)carve((size_t)(n + 1) * 4);
    int*   blk_sums = (int*)carve((size_t)256 * 4);
    float* dinv     = (float*)carve((size_t)n * 4);
    int*   epos     = (int*)carve((size_t)e * 4);
    unsigned short* W1t = (unsigned short*)carve((size_t)FDIM * HDIM * 2);
    unsigned short* W2t = (unsigned short*)carve((size_t)HDIM * HDIM * 2);
    int2*  csr      = (int2*)carve((size_t)e * 8);
    unsigned char* x_f8 = (unsigned char*)carve((size_t)n * FDIM);
    unsigned short* P = (unsigned short*)carve((size_t)n * HDIM * 2);
    unsigned char*  Q = (unsigned char*)carve((size_t)n * HDIM);
    float* pool     = (float*)carve((size_t)GG * HDIM * 4);
    unsigned short* a0b  = P;                       // [N,128] bf16
    unsigned short* a1b  = P;                       // [N,256] bf16 (a0b dead)
    unsigned char*  h1f8 = Q;                       // [N,256] fp8 e4m3
    (void)ws_size; (void)n_in; (void)in_sizes; (void)out_size;

    // deg must be zero before cast_hist's atomic histogram
    hipMemsetAsync(deg_i, 0, (size_t)n * 4, stream);
    // hist (FIRST, 1 edge/thread) + cast x (fp8) + W transposes + zero pool: one dispatch
    cast_hist<<<(CAST_TOTAL + 255) / 256, 256, 0, stream>>>(
        x, x_f8, W1, W1t, W2, W2t, pool, e_dst, deg_i, epos);
    scan_part<<<SCAN_NB, 256, 0, stream>>>(deg_i, row_off, blk_sums, dinv, n);
    scan_sums<<<1, 256, 0, stream>>>(blk_sums, SCAN_NB);
    scatter_kernel<<<1024, 256, 0, stream>>>(e_src, e_dst, row_off, blk_sums, epos, dinv, csr, e);

    dim3 gemm_grid((n + 127) / 128, 2);
    // L1: a0 = agg(x_f8) bf16; h1f8 = fp8(relu(a0 @ W1 + b1))
    gcn_agg128_fp8<<<(n + 3) / 4, 256, 0, stream>>>(x_f8, row_off, blk_sums, csr, dinv, a0b, n);
    gemm1_mfma_bias_relu<<<gemm_grid, 512, 0, stream>>>(a0b, W1t, b1, h1f8, n);
    // L2: a1 = agg(h1f8) bf16; pool += segsum(relu(a1 @ W2 + b2))
    gcn_agg256_fp8<<<(n + 3) / 4, 256, 0, stream>>>(h1f8, row_off, blk_sums, csr, dinv, a1b, n);
    gemm2_pool<<<gemm_grid, 512, 0, stream>>>(a1b, W2t, b2, batch, pool, n);
    // head
    head_kernel<<<GG, 256, 0, stream>>>(pool, batch, num_atoms, W3, b3, W4, b4, out, n);
}